// Round 2
// baseline (1102.111 us; speedup 1.0000x reference)
//
#include <hip/hip_runtime.h>

// SimpleRNN: B=4096, K=512, U=3, P=5, H=128, L=32, N_SUB=10
// 256 blocks x 512 threads (8 waves), 16 batch rows/block, 1 block/CU.
// "T-scheme": all GEMMs computed transposed (weights as MFMA A-operand,
// activations as B-operand) so D has batch-row in lane&15 and out-col in
// regs. LDS fragment buffers are lane-major: consumer lane l reads its 16B
// block at l*16 (conflict-free b128); producers write one ds_write_b64.
//
// R1: RK4 is linear in y: one substep == y <- max(M y, 0) with
// M = I + hA + h^2/2 A^2 + h^3/6 A^3 + h^4/24 A^4, collapsed via
// T = C*B (4x4 tridiag) to M = I5 + B*P*C.
// R2: (a) double-head MFMA: head A-frag rows (col&3) / 4+(col&3) make every
//     lane receive all 8 rates (m&3==reg for all quads) -> no ds_swizzle on
//     the chain. (b) M >= 0 entrywise for hs<=0.1, rates<=3 (off-diag
//     factors leading-path x (1-O(h*rates)) > 0), y>=0 -> clamps are exact
//     no-ops -> 10 substeps == 5 applications of M2 = M*M (halves substep
//     issue + chain depth). (c) s_setprio(1) around wave-7 serial phase-2.

#define KSTEPS 512
#define NTH 512

typedef short s16x8 __attribute__((ext_vector_type(8)));
typedef short s16x4 __attribute__((ext_vector_type(4)));
typedef float f32x4 __attribute__((ext_vector_type(4)));

__device__ __forceinline__ unsigned short f2bf(float f) {
  union { float f; unsigned u; } v; v.f = f;
  unsigned r = v.u + 0x7FFFu + ((v.u >> 16) & 1u);  // RNE
  return (unsigned short)(r >> 16);
}
__device__ __forceinline__ unsigned cvt2bf(float lo, float hi) {
  unsigned r;
  asm("v_cvt_pk_bf16_f32 %0, %1, %2" : "=v"(r) : "v"(lo), "v"(hi));
  return r;
}
__device__ __forceinline__ float ex2(float x) {
#if __has_builtin(__builtin_amdgcn_exp2f)
  return __builtin_amdgcn_exp2f(x);
#else
  return exp2f(x);
#endif
}
__device__ __forceinline__ float rcp_(float x) {
#if __has_builtin(__builtin_amdgcn_rcpf)
  return __builtin_amdgcn_rcpf(x);
#else
  return 1.0f / x;
#endif
}
__device__ __forceinline__ float sigm(float x) {
  return rcp_(1.0f + ex2(-1.44269504088896f * x));
}
__device__ __forceinline__ float tanh_(float x) {
  return fmaf(2.0f, rcp_(1.0f + ex2(-2.88539008177793f * x)), -1.0f);
}
__device__ __forceinline__ f32x4 splat4(float v) { f32x4 r = {v, v, v, v}; return r; }
__device__ __forceinline__ f32x4 MFMA(s16x8 a, s16x8 b, f32x4 c) {
  return __builtin_amdgcn_mfma_f32_16x16x32_bf16(a, b, c, 0, 0, 0);
}
__device__ __forceinline__ s16x8 bfrag_g(const float* __restrict__ src8) {
  s16x8 r;
#pragma unroll
  for (int j = 0; j < 8; ++j) r[j] = (short)f2bf(src8[j]);
  return r;
}

__global__ __launch_bounds__(NTH, 2) void rnn_scan_kernel(
    const float* __restrict__ y0, const float* __restrict__ u_seq,
    const float* __restrict__ dt_seq, const float* __restrict__ lift_W,
    const float* __restrict__ lift_b, const float* __restrict__ W_ih,
    const float* __restrict__ W_hh, const float* __restrict__ b_ih,
    const float* __restrict__ b_hh, const float* __restrict__ head_W,
    const float* __restrict__ head_b, const float* __restrict__ jumpW,
    float* __restrict__ y_out, float* __restrict__ th_out) {
  // lane-major fragment buffers: block (s*64 + q*16 + row) of 8 shorts holds
  // act[row][s*32 + q*8 .. +7]; consumer lane l frag s reads block s*64+l.
  __shared__ __align__(16) unsigned short s_Ah[4096];  // h: k=128 -> 4 frags
  __shared__ __align__(16) unsigned short s_Ax[1024];  // x: k=32  -> 1 frag
  __shared__ __align__(16) float s_thr[2][16][8];      // theta ring
  __shared__ __align__(16) float s_yr[2][16][8];       // y ring (padded)

  const int tid = threadIdx.x;
  const int w = tid >> 6;      // wave 0..7; wave 7 = critical wave
  const int lane = tid & 63;
  const int quad = lane >> 4;
  const int col = lane & 15;   // = batch row in the T-scheme
  const int r0 = blockIdx.x << 4;

  s16x8 zf;
#pragma unroll
  for (int j = 0; j < 8; ++j) zf[j] = 0;

  // ---- weight A-frags: A[m=out-col@lane&15][k=quad*8+j] ----
  s16x8 bih_r = bfrag_g(&W_ih[(w * 16 + col) * 32 + quad * 8]);
  s16x8 bih_z = bfrag_g(&W_ih[((8 + w) * 16 + col) * 32 + quad * 8]);
  s16x8 bih_n = bfrag_g(&W_ih[((16 + w) * 16 + col) * 32 + quad * 8]);
  s16x8 bhh_r[4], bhh_z[4], bhh_n[4], bhdF[4], bhdR[4];
#pragma unroll
  for (int s = 0; s < 4; ++s) {
    bhh_r[s] = bfrag_g(&W_hh[(w * 16 + col) * 128 + s * 32 + quad * 8]);
    bhh_z[s] = bfrag_g(&W_hh[((8 + w) * 16 + col) * 128 + s * 32 + quad * 8]);
    bhh_n[s] = bfrag_g(&W_hh[((16 + w) * 16 + col) * 128 + s * 32 + quad * 8]);
    // head rows replicated mod 4: D row m -> head_W row (m&3) = reg index,
    // so every (quad,lane) receives kf1..4 (F) / kr1..4 (R) directly.
    bhdF[s] = bfrag_g(&head_W[(col & 3) * 128 + s * 32 + quad * 8]);
    bhdR[s] = bfrag_g(&head_W[(4 + (col & 3)) * 128 + s * 32 + quad * 8]);
  }
  s16x8 blft0 = (quad == 0) ? bfrag_g(&lift_W[col * 8]) : zf;
  s16x8 blft1 = (quad == 0) ? bfrag_g(&lift_W[(16 + col) * 8]) : zf;

  // ---- per-(quad,i) biases (out-col dim now lives in regs+quad) ----
  f32x4 brz_r, brz_z, bn_iv, bn_hv, lbv0, lbv1, hbF, hbR;
#pragma unroll
  for (int i = 0; i < 4; ++i) {
    int g = w * 16 + quad * 4 + i;
    brz_r[i] = b_ih[g] + b_hh[g];
    brz_z[i] = b_ih[128 + g] + b_hh[128 + g];
    bn_iv[i] = b_ih[256 + g];
    bn_hv[i] = b_hh[256 + g];
    lbv0[i] = lift_b[quad * 4 + i];
    lbv1[i] = lift_b[16 + quad * 4 + i];
    hbF[i] = head_b[i];
    hbR[i] = head_b[4 + i];
  }
  float J[15];
#pragma unroll
  for (int i = 0; i < 15; ++i) J[i] = jumpW[i];

  // producer LDS byte offsets
  const int hwoff = (((w >> 1) * 64 + ((w & 1) * 2 + (quad >> 1)) * 16 + col) << 4) +
                    ((quad & 1) << 3);
  const int xw0 = ((((quad >> 1)) * 16 + col) << 4) + ((quad & 1) << 3);
  const int xw1 = (((2 + (quad >> 1)) * 16 + col) << 4) + ((quad & 1) << 3);

  // persistent state
  f32x4 ar = brz_r, az = brz_z, angi = bn_iv, angh = bn_hv;
  f32x4 h_reg = splat4(0.0f);
  float y[5] = {0.f, 0.f, 0.f, 0.f, 0.f};
  float uc0 = 0.f, uc1 = 0.f, uc2 = 0.f, dtc = 0.f;
  float un0 = 0.f, un1 = 0.f, un2 = 0.f, dtn = 0.f;

  // ---- prologue: wave 7 builds x(0) ----
  if (w == 7) {
    if (quad == 0) {
      const float* yp = &y0[(r0 + col) * 5];
#pragma unroll
      for (int i = 0; i < 5; ++i) y[i] = yp[i] + 0.01f;
      const float* up = &u_seq[((size_t)(r0 + col) * KSTEPS) * 3];
      uc0 = up[0]; uc1 = up[1]; uc2 = up[2];
      dtc = dt_seq[(size_t)(r0 + col) * KSTEPS];
    }
    s16x8 af = zf;
    if (quad == 0) {
      union { s16x8 v; unsigned u[4]; } afu;
      afu.u[0] = cvt2bf(uc0, uc1);
      afu.u[1] = cvt2bf(uc2, y[0]);
      afu.u[2] = cvt2bf(y[1], y[2]);
      afu.u[3] = cvt2bf(y[3], y[4]);
      af = afu.v;
    }
    f32x4 x0 = MFMA(blft0, af, lbv0);
    f32x4 x1 = MFMA(blft1, af, lbv1);
    f32x4 s0, s1;
#pragma unroll
    for (int i = 0; i < 4; ++i) {
      float v0 = x0[i]; s0[i] = v0 * sigm(v0);
      float v1 = x1[i]; s1[i] = v1 * sigm(v1);
    }
    uint2 xp0, xp1;
    xp0.x = cvt2bf(s0[0], s0[1]); xp0.y = cvt2bf(s0[2], s0[3]);
    xp1.x = cvt2bf(s1[0], s1[1]); xp1.y = cvt2bf(s1[2], s1[3]);
    *(uint2*)((char*)s_Ax + xw0) = xp0;
    *(uint2*)((char*)s_Ax + xw1) = xp1;
  }
  __syncthreads();  // B_x(0)

#pragma unroll 1
  for (int k = 0; k < KSTEPS; ++k) {
    // ======== phase 1: gi + gates + h stage (all waves) ========
    {
      s16x8 xf = *(const s16x8*)((const char*)s_Ax + lane * 16);
      ar = MFMA(bih_r, xf, ar);
      az = MFMA(bih_z, xf, az);
      angi = MFMA(bih_n, xf, angi);
    }
    if (w == 7 && quad == 0) {  // prefetch u/dt for step k+1
      int kn = (k + 1 < KSTEPS) ? k + 1 : KSTEPS - 1;
      const float* up = &u_seq[((size_t)(r0 + col) * KSTEPS + kn) * 3];
      un0 = up[0]; un1 = up[1]; un2 = up[2];
      dtn = dt_seq[(size_t)(r0 + col) * KSTEPS + kn];
    }
    {
      f32x4 hf;
#pragma unroll
      for (int i = 0; i < 4; ++i) {
        float r = sigm(ar[i]);
        float z = sigm(az[i]);
        float n = tanh_(fmaf(r, angh[i], angi[i]));
        float hn = fmaf(z, h_reg[i] - n, n);
        h_reg[i] = hn;
        hf[i] = hn;
      }
      uint2 hp;
      hp.x = cvt2bf(hf[0], hf[1]);
      hp.y = cvt2bf(hf[2], hf[3]);
      *(uint2*)((char*)s_Ah + hwoff) = hp;  // one b64, ~4-way (free-ish)
    }
    ar = brz_r; az = brz_z; angi = bn_iv; angh = bn_hv;  // reset for k+1
    __syncthreads();  // B_h

    // ======== phase 2 ========
    s16x8 ah[4];
#pragma unroll
    for (int s = 0; s < 4; ++s)
      ah[s] = *(const s16x8*)((const char*)s_Ah + (s * 64 + lane) * 16);

    if (w == 7) {
      __builtin_amdgcn_s_setprio(1);
      // double-head: every lane gets kf1..4 (F) and kr1..4 (R) directly
      f32x4 hdF0 = MFMA(bhdF[0], ah[0], hbF);
      f32x4 hdF1 = MFMA(bhdF[1], ah[1], splat4(0.0f));
      f32x4 hdR0 = MFMA(bhdR[0], ah[0], hbR);
      f32x4 hdR1 = MFMA(bhdR[1], ah[1], splat4(0.0f));
      hdF0 = MFMA(bhdF[2], ah[2], hdF0);
      hdF1 = MFMA(bhdF[3], ah[3], hdF1);
      hdR0 = MFMA(bhdR[2], ah[2], hdR0);
      hdR1 = MFMA(bhdR[3], ah[3], hdR1);
      // own gh(k+1) overlaps the head->theta latency
#pragma unroll
      for (int s = 0; s < 4; ++s) {
        ar = MFMA(bhh_r[s], ah[s], ar);
        az = MFMA(bhh_z[s], ah[s], az);
        angh = MFMA(bhh_n[s], ah[s], angh);
      }
      f32x4 hdF = hdF0 + hdF1;
      f32x4 hdR = hdR0 + hdR1;
      f32x4 tvF, tvR;
#pragma unroll
      for (int i = 0; i < 4; ++i) {
        tvF[i] = fmaf(2.99f, sigm(hdF[i]), 0.01f);
        tvR[i] = fmaf(2.99f, sigm(hdR[i]), 0.01f);
      }
      const int slot = k & 1;
      if (quad == 0) {
        *(f32x4*)&s_thr[slot][col][0] = tvF;
        *(f32x4*)&s_thr[slot][col][4] = tvR;
      }
      const float F0 = tvF[0], F1 = tvF[1], F2 = tvF[2], F3 = tvF[3];
      const float R0 = tvR[0], R1 = tvR[1], R2 = tvR[2], R3 = tvR[3];
      // jump + linear-RK4 (uniform execution; valid on quad0, benign elsewhere)
#pragma unroll
      for (int i = 0; i < 5; ++i)
        y[i] += uc0 * J[i] + uc1 * J[5 + i] + uc2 * J[10 + i];
      const float hs = dtc * 0.1f;

      // ---- build M = I5 + B*P*C once (exact RK4 polynomial) ----
      // T = C*B (4x4 tridiag): diag TDj=-(Fj+Rj), sub T[j][j-1]=Fj, sup T[j][j+1]=Rj
      const float TD0 = -(F0 + R0), TD1 = -(F1 + R1), TD2 = -(F2 + R2), TD3 = -(F3 + R3);
      const float c4 = 0.25f * hs, c3 = hs * (1.0f / 3.0f), c2 = 0.5f * hs;
      // Z3 = I + c4*T (tridiag)
      const float d30 = fmaf(c4, TD0, 1.f), d31 = fmaf(c4, TD1, 1.f);
      const float d32 = fmaf(c4, TD2, 1.f), d33 = fmaf(c4, TD3, 1.f);
      const float l31 = c4 * F1, l32 = c4 * F2, l33 = c4 * F3;
      const float u30 = c4 * R0, u31 = c4 * R1, u32 = c4 * R2;
      // W3 = T*Z3 (band 2)
      const float w300 = fmaf(TD0, d30, R0 * l31);
      const float w301 = fmaf(TD0, u30, R0 * d31);
      const float w302 = R0 * u31;
      const float w310 = fmaf(F1, d30, TD1 * l31);
      const float w311 = fmaf(F1, u30, fmaf(TD1, d31, R1 * l32));
      const float w312 = fmaf(TD1, u31, R1 * d32);
      const float w313 = R1 * u32;
      const float w320 = F2 * l31;
      const float w321 = fmaf(F2, d31, TD2 * l32);
      const float w322 = fmaf(F2, u31, fmaf(TD2, d32, R2 * l33));
      const float w323 = fmaf(TD2, u32, R2 * d33);
      const float w331 = F3 * l32;
      const float w332 = fmaf(F3, d32, TD3 * l33);
      const float w333 = fmaf(F3, u32, TD3 * d33);
      // Z2 = I + c3*W3 (band 2; [0][3]=[3][0]=0)
      const float e20 = fmaf(c3, w300, 1.f), e21 = fmaf(c3, w311, 1.f);
      const float e22 = fmaf(c3, w322, 1.f), e23 = fmaf(c3, w333, 1.f);
      const float a201 = c3 * w301, a202 = c3 * w302;
      const float a210 = c3 * w310, a212 = c3 * w312, a213 = c3 * w313;
      const float a220 = c3 * w320, a221 = c3 * w321, a223 = c3 * w323;
      const float a231 = c3 * w331, a232 = c3 * w332;
      // W2 = T*Z2 (full 4x4)
      const float w200 = fmaf(TD0, e20, R0 * a210);
      const float w201 = fmaf(TD0, a201, R0 * e21);
      const float w202 = fmaf(TD0, a202, R0 * a212);
      const float w203 = R0 * a213;
      const float w210 = fmaf(F1, e20, fmaf(TD1, a210, R1 * a220));
      const float w211 = fmaf(F1, a201, fmaf(TD1, e21, R1 * a221));
      const float w212 = fmaf(F1, a202, fmaf(TD1, a212, R1 * e22));
      const float w213 = fmaf(TD1, a213, R1 * a223);
      const float w220 = fmaf(F2, a210, TD2 * a220);
      const float w221 = fmaf(F2, e21, fmaf(TD2, a221, R2 * a231));
      const float w222 = fmaf(F2, a212, fmaf(TD2, e22, R2 * a232));
      const float w223 = fmaf(F2, a213, fmaf(TD2, a223, R2 * e23));
      const float w230 = F3 * a220;
      const float w231 = fmaf(F3, a221, TD3 * a231);
      const float w232 = fmaf(F3, e22, TD3 * a232);
      const float w233 = fmaf(F3, a223, TD3 * e23);
      // Z1 = I + c2*W2 (full)
      const float z100 = fmaf(c2, w200, 1.f), z101 = c2 * w201, z102 = c2 * w202, z103 = c2 * w203;
      const float z110 = c2 * w210, z111 = fmaf(c2, w211, 1.f), z112 = c2 * w212, z113 = c2 * w213;
      const float z120 = c2 * w220, z121 = c2 * w221, z122 = fmaf(c2, w222, 1.f), z123 = c2 * w223;
      const float z130 = c2 * w230, z131 = c2 * w231, z132 = c2 * w232, z133 = fmaf(c2, w233, 1.f);
      // PC = (hs*Z1)*C, C[l][l]=F_l, C[l][l+1]=-R_l (hs folded into FH/RH)
      const float FH0 = hs * F0, FH1 = hs * F1, FH2 = hs * F2, FH3 = hs * F3;
      const float RH0 = hs * R0, RH1 = hs * R1, RH2 = hs * R2, RH3 = hs * R3;
      const float pc00 = z100 * FH0;
      const float pc01 = fmaf(z101, FH1, -(z100 * RH0));
      const float pc02 = fmaf(z102, FH2, -(z101 * RH1));
      const float pc03 = fmaf(z103, FH3, -(z102 * RH2));
      const float pc04 = -(z103 * RH3);
      const float pc10 = z110 * FH0;
      const float pc11 = fmaf(z111, FH1, -(z110 * RH0));
      const float pc12 = fmaf(z112, FH2, -(z111 * RH1));
      const float pc13 = fmaf(z113, FH3, -(z112 * RH2));
      const float pc14 = -(z113 * RH3);
      const float pc20 = z120 * FH0;
      const float pc21 = fmaf(z121, FH1, -(z120 * RH0));
      const float pc22 = fmaf(z122, FH2, -(z121 * RH1));
      const float pc23 = fmaf(z123, FH3, -(z122 * RH2));
      const float pc24 = -(z123 * RH3);
      const float pc30 = z130 * FH0;
      const float pc31 = fmaf(z131, FH1, -(z130 * RH0));
      const float pc32 = fmaf(z132, FH2, -(z131 * RH1));
      const float pc33 = fmaf(z133, FH3, -(z132 * RH2));
      const float pc34 = -(z133 * RH3);
      // M = I5 + B*PC (B row0=-PC0, rowi=PC(i-1)-PCi, row4=PC3)
      float Mm[5][5];
      Mm[0][0] = 1.0f - pc00; Mm[0][1] = -pc01; Mm[0][2] = -pc02; Mm[0][3] = -pc03; Mm[0][4] = -pc04;
      Mm[1][0] = pc00 - pc10; Mm[1][1] = 1.0f + (pc01 - pc11); Mm[1][2] = pc02 - pc12;
      Mm[1][3] = pc03 - pc13; Mm[1][4] = pc04 - pc14;
      Mm[2][0] = pc10 - pc20; Mm[2][1] = pc11 - pc21; Mm[2][2] = 1.0f + (pc12 - pc22);
      Mm[2][3] = pc13 - pc23; Mm[2][4] = pc14 - pc24;
      Mm[3][0] = pc20 - pc30; Mm[3][1] = pc21 - pc31; Mm[3][2] = pc22 - pc32;
      Mm[3][3] = 1.0f + (pc23 - pc33); Mm[3][4] = pc24 - pc34;
      Mm[4][0] = pc30; Mm[4][1] = pc31; Mm[4][2] = pc32; Mm[4][3] = pc33;
      Mm[4][4] = 1.0f + pc34;
      // M2 = M*M (M >= 0 entrywise here, y >= 0 -> clamps are exact no-ops,
      // so 10 M-substeps == 5 M2-substeps)
      float M2[5][5];
#pragma unroll
      for (int i = 0; i < 5; ++i) {
#pragma unroll
        for (int j = 0; j < 5; ++j) {
          float acc = Mm[i][0] * Mm[0][j];
#pragma unroll
          for (int l = 1; l < 5; ++l) acc = fmaf(Mm[i][l], Mm[l][j], acc);
          M2[i][j] = acc;
        }
      }
      // ---- 5 double-substeps: y <- max(M2 y, 0) ----
#pragma unroll
      for (int ss = 0; ss < 5; ++ss) {
        float n[5];
#pragma unroll
        for (int i = 0; i < 5; ++i) {
          float acc = M2[i][0] * y[0];
#pragma unroll
          for (int j = 1; j < 5; ++j) acc = fmaf(M2[i][j], y[j], acc);
          n[i] = acc;
        }
#pragma unroll
        for (int i = 0; i < 5; ++i) y[i] = fmaxf(n[i], 0.0f);
      }
      if (quad == 0) {
        *(f32x4*)&s_yr[slot][col][0] = *(const f32x4*)&y[0];
        s_yr[slot][col][4] = y[4];
      }
      // feat(k+1) -> liftT -> silu -> x stage
      if (k + 1 < KSTEPS) {
        s16x8 af = zf;
        if (quad == 0) {
          union { s16x8 v; unsigned u[4]; } afu;
          afu.u[0] = cvt2bf(un0, un1);
          afu.u[1] = cvt2bf(un2, y[0]);
          afu.u[2] = cvt2bf(y[1], y[2]);
          afu.u[3] = cvt2bf(y[3], y[4]);
          af = afu.v;
        }
        f32x4 x0 = MFMA(blft0, af, lbv0);
        f32x4 x1 = MFMA(blft1, af, lbv1);
        f32x4 s0, s1;
#pragma unroll
        for (int i = 0; i < 4; ++i) {
          float v0 = x0[i]; s0[i] = v0 * sigm(v0);
          float v1 = x1[i]; s1[i] = v1 * sigm(v1);
        }
        uint2 xp0, xp1;
        xp0.x = cvt2bf(s0[0], s0[1]); xp0.y = cvt2bf(s0[2], s0[3]);
        xp1.x = cvt2bf(s1[0], s1[1]); xp1.y = cvt2bf(s1[2], s1[3]);
        *(uint2*)((char*)s_Ax + xw0) = xp0;
        *(uint2*)((char*)s_Ax + xw1) = xp1;
      }
      uc0 = un0; uc1 = un1; uc2 = un2; dtc = dtn;
      __builtin_amdgcn_s_setprio(0);
    } else {
      // gh(k+1) for this wave's tile (in wave-7's shadow)
#pragma unroll
      for (int s = 0; s < 4; ++s) {
        ar = MFMA(bhh_r[s], ah[s], ar);
        az = MFMA(bhh_z[s], ah[s], az);
        angh = MFMA(bhh_n[s], ah[s], angh);
      }
      if (w == 0 && k > 0) {  // store step k-1 outputs from the ring
        const int km = k - 1, slot = km & 1;
#pragma unroll
        for (int rep = 0; rep < 2; ++rep) {
          int idx = lane + rep * 64;
          int row = idx >> 3, c = idx & 7;
          th_out[((size_t)(r0 + row) * KSTEPS + km) * 8 + c] = s_thr[slot][row][c];
        }
        {
          int idx = lane;
          int row = idx / 5, c = idx - row * 5;
          y_out[((size_t)(r0 + row) * KSTEPS + km) * 5 + c] = s_yr[slot][row][c];
        }
        if (lane < 16) {
          int idx = 64 + lane;
          int row = idx / 5, c = idx - row * 5;
          y_out[((size_t)(r0 + row) * KSTEPS + km) * 5 + c] = s_yr[slot][row][c];
        }
      }
    }
    __syncthreads();  // B_x: x(k+1) staged, s_Ah reusable
  }

  // flush step-511 outputs
  if (w == 0) {
    const int km = KSTEPS - 1, slot = km & 1;
#pragma unroll
    for (int rep = 0; rep < 2; ++rep) {
      int idx = lane + rep * 64;
      int row = idx >> 3, c = idx & 7;
      th_out[((size_t)(r0 + row) * KSTEPS + km) * 8 + c] = s_thr[slot][row][c];
    }
    {
      int idx = lane;
      int row = idx / 5, c = idx - row * 5;
      y_out[((size_t)(r0 + row) * KSTEPS + km) * 5 + c] = s_yr[slot][row][c];
    }
    if (lane < 16) {
      int idx = 64 + lane;
      int row = idx / 5, c = idx - row * 5;
      y_out[((size_t)(r0 + row) * KSTEPS + km) * 5 + c] = s_yr[slot][row][c];
    }
  }
}

extern "C" void kernel_launch(void* const* d_in, const int* in_sizes, int n_in,
                              void* d_out, int out_size, void* d_ws, size_t ws_size,
                              hipStream_t stream) {
  const float* y0 = (const float*)d_in[0];
  const float* u_seq = (const float*)d_in[1];
  const float* dt_seq = (const float*)d_in[2];
  const float* lift_W = (const float*)d_in[3];
  const float* lift_b = (const float*)d_in[4];
  const float* W_ih = (const float*)d_in[5];
  const float* W_hh = (const float*)d_in[6];
  const float* b_ih = (const float*)d_in[7];
  const float* b_hh = (const float*)d_in[8];
  const float* head_W = (const float*)d_in[9];
  const float* head_b = (const float*)d_in[10];
  const float* jumpW = (const float*)d_in[11];

  float* y_out = (float*)d_out;                    // (4096, 512, 5)
  float* th_out = y_out + (size_t)4096 * 512 * 5;  // (4096, 512, 8)

  rnn_scan_kernel<<<dim3(256), dim3(NTH), 0, stream>>>(
      y0, u_seq, dt_seq, lift_W, lift_b, W_ih, W_hh, b_ih, b_hh, head_W,
      head_b, jumpW, y_out, th_out);
}

// Round 3
// 1023.511 us; speedup vs baseline: 1.0768x; 1.0768x over previous
//
#include <hip/hip_runtime.h>

// SimpleRNN: B=4096, K=512, U=3, P=5, H=128, L=32, N_SUB=10
// 256 blocks x 512 threads (8 waves), 16 batch rows/block, 1 block/CU.
// "T-scheme": all GEMMs computed transposed (weights as MFMA A-operand,
// activations as B-operand) so D has batch-row in lane&15 and out-col in
// regs. LDS fragment buffers are lane-major: consumer lane l reads its 16B
// block at l*16 (conflict-free b128); producers write one ds_write_b64.
//
// R1: RK4 is linear in y: substep == y <- max(M y, 0), M = RK4 poly of hs*A,
//     collapsed via T = C*B (4x4 tridiag) to M = I5 + B*P*C, P = hs*Z1.
// R2: double-head MFMA gives every lane all 8 rates (no ds_swizzle).
// R3: (a) flux-space iteration: w~_s = hs*C*y_s (4-dim) evolves as
//     w~ <- G w~ with G = I + hs*T*Z1 (4x4); y10 = y0 + B*Z1*sum(w~_s).
//     Clamp is a no-op (M>=0 entrywise, y>=0), so no fmax and the substep
//     matvec is 16 fma not 25: ~64 fewer serial ops on the critical wave.
//     (b) u/dt staged by wave 1 into a 3-slot LDS ring (loads k+2 during its
//     phase-2 slack; vmcnt drain shadowed by wave-7's serial section).
//     Wave 7 reads 2x ds_read_b128 instead of issuing global loads whose
//     drain stalled all waves at B_h.

#define KSTEPS 512
#define NTH 512

typedef short s16x8 __attribute__((ext_vector_type(8)));
typedef short s16x4 __attribute__((ext_vector_type(4)));
typedef float f32x4 __attribute__((ext_vector_type(4)));

__device__ __forceinline__ unsigned short f2bf(float f) {
  union { float f; unsigned u; } v; v.f = f;
  unsigned r = v.u + 0x7FFFu + ((v.u >> 16) & 1u);  // RNE
  return (unsigned short)(r >> 16);
}
__device__ __forceinline__ unsigned cvt2bf(float lo, float hi) {
  unsigned r;
  asm("v_cvt_pk_bf16_f32 %0, %1, %2" : "=v"(r) : "v"(lo), "v"(hi));
  return r;
}
__device__ __forceinline__ float ex2(float x) {
#if __has_builtin(__builtin_amdgcn_exp2f)
  return __builtin_amdgcn_exp2f(x);
#else
  return exp2f(x);
#endif
}
__device__ __forceinline__ float rcp_(float x) {
#if __has_builtin(__builtin_amdgcn_rcpf)
  return __builtin_amdgcn_rcpf(x);
#else
  return 1.0f / x;
#endif
}
__device__ __forceinline__ float sigm(float x) {
  return rcp_(1.0f + ex2(-1.44269504088896f * x));
}
__device__ __forceinline__ float tanh_(float x) {
  return fmaf(2.0f, rcp_(1.0f + ex2(-2.88539008177793f * x)), -1.0f);
}
__device__ __forceinline__ f32x4 splat4(float v) { f32x4 r = {v, v, v, v}; return r; }
__device__ __forceinline__ f32x4 MFMA(s16x8 a, s16x8 b, f32x4 c) {
  return __builtin_amdgcn_mfma_f32_16x16x32_bf16(a, b, c, 0, 0, 0);
}
__device__ __forceinline__ s16x8 bfrag_g(const float* __restrict__ src8) {
  s16x8 r;
#pragma unroll
  for (int j = 0; j < 8; ++j) r[j] = (short)f2bf(src8[j]);
  return r;
}

__global__ __launch_bounds__(NTH, 2) void rnn_scan_kernel(
    const float* __restrict__ y0, const float* __restrict__ u_seq,
    const float* __restrict__ dt_seq, const float* __restrict__ lift_W,
    const float* __restrict__ lift_b, const float* __restrict__ W_ih,
    const float* __restrict__ W_hh, const float* __restrict__ b_ih,
    const float* __restrict__ b_hh, const float* __restrict__ head_W,
    const float* __restrict__ head_b, const float* __restrict__ jumpW,
    float* __restrict__ y_out, float* __restrict__ th_out) {
  // lane-major fragment buffers: block (s*64 + q*16 + row) of 8 shorts holds
  // act[row][s*32 + q*8 .. +7]; consumer lane l frag s reads block s*64+l.
  __shared__ __align__(16) unsigned short s_Ah[4096];  // h: k=128 -> 4 frags
  __shared__ __align__(16) unsigned short s_Ax[1024];  // x: k=32  -> 1 frag
  __shared__ __align__(16) float s_thr[2][16][8];      // theta ring
  __shared__ __align__(16) float s_yr[2][16][8];       // y ring (padded)
  __shared__ __align__(16) float s_ur[3][16][4];       // u/dt ring (3 slots)

  const int tid = threadIdx.x;
  const int w = tid >> 6;      // wave 0..7; wave 7 = critical wave
  const int lane = tid & 63;
  const int quad = lane >> 4;
  const int col = lane & 15;   // = batch row in the T-scheme
  const int r0 = blockIdx.x << 4;

  s16x8 zf;
#pragma unroll
  for (int j = 0; j < 8; ++j) zf[j] = 0;

  // ---- weight A-frags: A[m=out-col@lane&15][k=quad*8+j] ----
  s16x8 bih_r = bfrag_g(&W_ih[(w * 16 + col) * 32 + quad * 8]);
  s16x8 bih_z = bfrag_g(&W_ih[((8 + w) * 16 + col) * 32 + quad * 8]);
  s16x8 bih_n = bfrag_g(&W_ih[((16 + w) * 16 + col) * 32 + quad * 8]);
  s16x8 bhh_r[4], bhh_z[4], bhh_n[4], bhdF[4], bhdR[4];
#pragma unroll
  for (int s = 0; s < 4; ++s) {
    bhh_r[s] = bfrag_g(&W_hh[(w * 16 + col) * 128 + s * 32 + quad * 8]);
    bhh_z[s] = bfrag_g(&W_hh[((8 + w) * 16 + col) * 128 + s * 32 + quad * 8]);
    bhh_n[s] = bfrag_g(&W_hh[((16 + w) * 16 + col) * 128 + s * 32 + quad * 8]);
    // head rows replicated mod 4: D row m -> head_W row (m&3) = reg index,
    // so every (quad,lane) receives kf1..4 (F) / kr1..4 (R) directly.
    bhdF[s] = bfrag_g(&head_W[(col & 3) * 128 + s * 32 + quad * 8]);
    bhdR[s] = bfrag_g(&head_W[(4 + (col & 3)) * 128 + s * 32 + quad * 8]);
  }
  s16x8 blft0 = (quad == 0) ? bfrag_g(&lift_W[col * 8]) : zf;
  s16x8 blft1 = (quad == 0) ? bfrag_g(&lift_W[(16 + col) * 8]) : zf;

  // ---- per-(quad,i) biases (out-col dim now lives in regs+quad) ----
  f32x4 brz_r, brz_z, bn_iv, bn_hv, lbv0, lbv1, hbF, hbR;
#pragma unroll
  for (int i = 0; i < 4; ++i) {
    int g = w * 16 + quad * 4 + i;
    brz_r[i] = b_ih[g] + b_hh[g];
    brz_z[i] = b_ih[128 + g] + b_hh[128 + g];
    bn_iv[i] = b_ih[256 + g];
    bn_hv[i] = b_hh[256 + g];
    lbv0[i] = lift_b[quad * 4 + i];
    lbv1[i] = lift_b[16 + quad * 4 + i];
    hbF[i] = head_b[i];
    hbR[i] = head_b[4 + i];
  }
  float J[15];
#pragma unroll
  for (int i = 0; i < 15; ++i) J[i] = jumpW[i];

  // producer LDS byte offsets
  const int hwoff = (((w >> 1) * 64 + ((w & 1) * 2 + (quad >> 1)) * 16 + col) << 4) +
                    ((quad & 1) << 3);
  const int xw0 = ((((quad >> 1)) * 16 + col) << 4) + ((quad & 1) << 3);
  const int xw1 = (((2 + (quad >> 1)) * 16 + col) << 4) + ((quad & 1) << 3);

  // persistent state
  f32x4 ar = brz_r, az = brz_z, angi = bn_iv, angh = bn_hv;
  f32x4 h_reg = splat4(0.0f);
  float y[5] = {0.f, 0.f, 0.f, 0.f, 0.f};

  // ---- prologue ----
  // wave 1: stage u/dt for steps 0 and 1 into the LDS ring
  if (w == 1 && lane < 16) {
#pragma unroll
    for (int pk = 0; pk < 2; ++pk) {
      const float* up = &u_seq[((size_t)(r0 + lane) * KSTEPS + pk) * 3];
      f32x4 uv;
      uv[0] = up[0]; uv[1] = up[1]; uv[2] = up[2];
      uv[3] = dt_seq[(size_t)(r0 + lane) * KSTEPS + pk];
      *(f32x4*)&s_ur[pk][lane][0] = uv;
    }
  }
  // wave 7 builds x(0)
  if (w == 7) {
    float uc0 = 0.f, uc1 = 0.f, uc2 = 0.f;
    if (quad == 0) {
      const float* yp = &y0[(r0 + col) * 5];
#pragma unroll
      for (int i = 0; i < 5; ++i) y[i] = yp[i] + 0.01f;
      const float* up = &u_seq[((size_t)(r0 + col) * KSTEPS) * 3];
      uc0 = up[0]; uc1 = up[1]; uc2 = up[2];
    }
    s16x8 af = zf;
    if (quad == 0) {
      union { s16x8 v; unsigned u[4]; } afu;
      afu.u[0] = cvt2bf(uc0, uc1);
      afu.u[1] = cvt2bf(uc2, y[0]);
      afu.u[2] = cvt2bf(y[1], y[2]);
      afu.u[3] = cvt2bf(y[3], y[4]);
      af = afu.v;
    }
    f32x4 x0 = MFMA(blft0, af, lbv0);
    f32x4 x1 = MFMA(blft1, af, lbv1);
    f32x4 s0, s1;
#pragma unroll
    for (int i = 0; i < 4; ++i) {
      float v0 = x0[i]; s0[i] = v0 * sigm(v0);
      float v1 = x1[i]; s1[i] = v1 * sigm(v1);
    }
    uint2 xp0, xp1;
    xp0.x = cvt2bf(s0[0], s0[1]); xp0.y = cvt2bf(s0[2], s0[3]);
    xp1.x = cvt2bf(s1[0], s1[1]); xp1.y = cvt2bf(s1[2], s1[3]);
    *(uint2*)((char*)s_Ax + xw0) = xp0;
    *(uint2*)((char*)s_Ax + xw1) = xp1;
  }
  __syncthreads();  // B_x(0)

  int sA = 0, sB = 1, sC = 2;  // ring slots: k%3, (k+1)%3, (k+2)%3

#pragma unroll 1
  for (int k = 0; k < KSTEPS; ++k) {
    // ======== phase 1: gi + gates + h stage (all waves) ========
    {
      s16x8 xf = *(const s16x8*)((const char*)s_Ax + lane * 16);
      ar = MFMA(bih_r, xf, ar);
      az = MFMA(bih_z, xf, az);
      angi = MFMA(bih_n, xf, angi);
    }
    {
      f32x4 hf;
#pragma unroll
      for (int i = 0; i < 4; ++i) {
        float r = sigm(ar[i]);
        float z = sigm(az[i]);
        float n = tanh_(fmaf(r, angh[i], angi[i]));
        float hn = fmaf(z, h_reg[i] - n, n);
        h_reg[i] = hn;
        hf[i] = hn;
      }
      uint2 hp;
      hp.x = cvt2bf(hf[0], hf[1]);
      hp.y = cvt2bf(hf[2], hf[3]);
      *(uint2*)((char*)s_Ah + hwoff) = hp;  // one b64, ~4-way (free-ish)
    }
    ar = brz_r; az = brz_z; angi = bn_iv; angh = bn_hv;  // reset for k+1
    __syncthreads();  // B_h

    // ======== phase 2 ========
    s16x8 ah[4];
#pragma unroll
    for (int s = 0; s < 4; ++s)
      ah[s] = *(const s16x8*)((const char*)s_Ah + (s * 64 + lane) * 16);

    if (w == 7) {
      __builtin_amdgcn_s_setprio(1);
      // u(k)/dt(k) and u(k+1) from the LDS ring (latency hidden under head)
      f32x4 urk = *(const f32x4*)&s_ur[sA][col][0];
      f32x4 urk1 = *(const f32x4*)&s_ur[sB][col][0];
      // double-head: every lane gets kf1..4 (F) and kr1..4 (R) directly
      f32x4 hdF0 = MFMA(bhdF[0], ah[0], hbF);
      f32x4 hdF1 = MFMA(bhdF[1], ah[1], splat4(0.0f));
      f32x4 hdR0 = MFMA(bhdR[0], ah[0], hbR);
      f32x4 hdR1 = MFMA(bhdR[1], ah[1], splat4(0.0f));
      hdF0 = MFMA(bhdF[2], ah[2], hdF0);
      hdF1 = MFMA(bhdF[3], ah[3], hdF1);
      hdR0 = MFMA(bhdR[2], ah[2], hdR0);
      hdR1 = MFMA(bhdR[3], ah[3], hdR1);
      // own gh(k+1) overlaps the head->theta latency
#pragma unroll
      for (int s = 0; s < 4; ++s) {
        ar = MFMA(bhh_r[s], ah[s], ar);
        az = MFMA(bhh_z[s], ah[s], az);
        angh = MFMA(bhh_n[s], ah[s], angh);
      }
      f32x4 hdF = hdF0 + hdF1;
      f32x4 hdR = hdR0 + hdR1;
      f32x4 tvF, tvR;
#pragma unroll
      for (int i = 0; i < 4; ++i) {
        tvF[i] = fmaf(2.99f, sigm(hdF[i]), 0.01f);
        tvR[i] = fmaf(2.99f, sigm(hdR[i]), 0.01f);
      }
      const int slot = k & 1;
      if (quad == 0) {
        *(f32x4*)&s_thr[slot][col][0] = tvF;
        *(f32x4*)&s_thr[slot][col][4] = tvR;
      }
      const float F0 = tvF[0], F1 = tvF[1], F2 = tvF[2], F3 = tvF[3];
      const float R0 = tvR[0], R1 = tvR[1], R2 = tvR[2], R3 = tvR[3];
      // jump (uniform execution; valid on quad0, benign elsewhere)
#pragma unroll
      for (int i = 0; i < 5; ++i)
        y[i] += urk[0] * J[i] + urk[1] * J[5 + i] + urk[2] * J[10 + i];
      const float hs = urk[3] * 0.1f;

      // ---- Z1 = I + c2 T(I + c3 T(I + c4 T)) (exact RK4 polynomial core) ----
      // T tridiag: diag TDj=-(Fj+Rj), sub T[j][j-1]=Fj, sup T[j][j+1]=Rj
      const float TD0 = -(F0 + R0), TD1 = -(F1 + R1), TD2 = -(F2 + R2), TD3 = -(F3 + R3);
      const float c4 = 0.25f * hs, c3 = hs * (1.0f / 3.0f), c2 = 0.5f * hs;
      // Z3 = I + c4*T (tridiag)
      const float d30 = fmaf(c4, TD0, 1.f), d31 = fmaf(c4, TD1, 1.f);
      const float d32 = fmaf(c4, TD2, 1.f), d33 = fmaf(c4, TD3, 1.f);
      const float l31 = c4 * F1, l32 = c4 * F2, l33 = c4 * F3;
      const float u30 = c4 * R0, u31 = c4 * R1, u32 = c4 * R2;
      // W3 = T*Z3 (band 2)
      const float w300 = fmaf(TD0, d30, R0 * l31);
      const float w301 = fmaf(TD0, u30, R0 * d31);
      const float w302 = R0 * u31;
      const float w310 = fmaf(F1, d30, TD1 * l31);
      const float w311 = fmaf(F1, u30, fmaf(TD1, d31, R1 * l32));
      const float w312 = fmaf(TD1, u31, R1 * d32);
      const float w313 = R1 * u32;
      const float w320 = F2 * l31;
      const float w321 = fmaf(F2, d31, TD2 * l32);
      const float w322 = fmaf(F2, u31, fmaf(TD2, d32, R2 * l33));
      const float w323 = fmaf(TD2, u32, R2 * d33);
      const float w331 = F3 * l32;
      const float w332 = fmaf(F3, d32, TD3 * l33);
      const float w333 = fmaf(F3, u32, TD3 * d33);
      // Z2 = I + c3*W3 (band 2; [0][3]=[3][0]=0)
      const float e20 = fmaf(c3, w300, 1.f), e21 = fmaf(c3, w311, 1.f);
      const float e22 = fmaf(c3, w322, 1.f), e23 = fmaf(c3, w333, 1.f);
      const float a201 = c3 * w301, a202 = c3 * w302;
      const float a210 = c3 * w310, a212 = c3 * w312, a213 = c3 * w313;
      const float a220 = c3 * w320, a221 = c3 * w321, a223 = c3 * w323;
      const float a231 = c3 * w331, a232 = c3 * w332;
      // W2 = T*Z2 (full 4x4)
      const float w200 = fmaf(TD0, e20, R0 * a210);
      const float w201 = fmaf(TD0, a201, R0 * e21);
      const float w202 = fmaf(TD0, a202, R0 * a212);
      const float w203 = R0 * a213;
      const float w210 = fmaf(F1, e20, fmaf(TD1, a210, R1 * a220));
      const float w211 = fmaf(F1, a201, fmaf(TD1, e21, R1 * a221));
      const float w212 = fmaf(F1, a202, fmaf(TD1, a212, R1 * e22));
      const float w213 = fmaf(TD1, a213, R1 * a223);
      const float w220 = fmaf(F2, a210, TD2 * a220);
      const float w221 = fmaf(F2, e21, fmaf(TD2, a221, R2 * a231));
      const float w222 = fmaf(F2, a212, fmaf(TD2, e22, R2 * a232));
      const float w223 = fmaf(F2, a213, fmaf(TD2, a223, R2 * e23));
      const float w230 = F3 * a220;
      const float w231 = fmaf(F3, a221, TD3 * a231);
      const float w232 = fmaf(F3, e22, TD3 * a232);
      const float w233 = fmaf(F3, a223, TD3 * e23);
      // Z1 = I + c2*W2 (full)
      const float z100 = fmaf(c2, w200, 1.f), z101 = c2 * w201, z102 = c2 * w202, z103 = c2 * w203;
      const float z110 = c2 * w210, z111 = fmaf(c2, w211, 1.f), z112 = c2 * w212, z113 = c2 * w213;
      const float z120 = c2 * w220, z121 = c2 * w221, z122 = fmaf(c2, w222, 1.f), z123 = c2 * w223;
      const float z130 = c2 * w230, z131 = c2 * w231, z132 = c2 * w232, z133 = fmaf(c2, w233, 1.f);
      // ---- flux-space: Q = T*Z1, G = I + hs*Q ----
      const float q00 = fmaf(TD0, z100, R0 * z110);
      const float q01 = fmaf(TD0, z101, R0 * z111);
      const float q02 = fmaf(TD0, z102, R0 * z112);
      const float q03 = fmaf(TD0, z103, R0 * z113);
      const float q10 = fmaf(F1, z100, fmaf(TD1, z110, R1 * z120));
      const float q11 = fmaf(F1, z101, fmaf(TD1, z111, R1 * z121));
      const float q12 = fmaf(F1, z102, fmaf(TD1, z112, R1 * z122));
      const float q13 = fmaf(F1, z103, fmaf(TD1, z113, R1 * z123));
      const float q20 = fmaf(F2, z110, fmaf(TD2, z120, R2 * z130));
      const float q21 = fmaf(F2, z111, fmaf(TD2, z121, R2 * z131));
      const float q22 = fmaf(F2, z112, fmaf(TD2, z122, R2 * z132));
      const float q23 = fmaf(F2, z113, fmaf(TD2, z123, R2 * z133));
      const float q30 = fmaf(F3, z120, TD3 * z130);
      const float q31 = fmaf(F3, z121, TD3 * z131);
      const float q32 = fmaf(F3, z122, TD3 * z132);
      const float q33 = fmaf(F3, z123, TD3 * z133);
      const float g00 = fmaf(hs, q00, 1.f), g01 = hs * q01, g02 = hs * q02, g03 = hs * q03;
      const float g10 = hs * q10, g11 = fmaf(hs, q11, 1.f), g12 = hs * q12, g13 = hs * q13;
      const float g20 = hs * q20, g21 = hs * q21, g22 = fmaf(hs, q22, 1.f), g23 = hs * q23;
      const float g30 = hs * q30, g31 = hs * q31, g32 = hs * q32, g33 = fmaf(hs, q33, 1.f);
      // w~0 = hs*C*y (after jump); clamp is a no-op (M>=0, y>=0)
      const float FH0 = hs * F0, FH1 = hs * F1, FH2 = hs * F2, FH3 = hs * F3;
      const float RH0 = hs * R0, RH1 = hs * R1, RH2 = hs * R2, RH3 = hs * R3;
      float w0 = fmaf(FH0, y[0], -(RH0 * y[1]));
      float w1 = fmaf(FH1, y[1], -(RH1 * y[2]));
      float w2 = fmaf(FH2, y[2], -(RH2 * y[3]));
      float w3 = fmaf(FH3, y[3], -(RH3 * y[4]));
      float a0 = w0, a1 = w1, a2 = w2, a3 = w3;
#pragma unroll
      for (int ss = 0; ss < 9; ++ss) {
        float t0 = fmaf(g00, w0, fmaf(g01, w1, fmaf(g02, w2, g03 * w3)));
        float t1 = fmaf(g10, w0, fmaf(g11, w1, fmaf(g12, w2, g13 * w3)));
        float t2 = fmaf(g20, w0, fmaf(g21, w1, fmaf(g22, w2, g23 * w3)));
        float t3 = fmaf(g30, w0, fmaf(g31, w1, fmaf(g32, w2, g33 * w3)));
        w0 = t0; w1 = t1; w2 = t2; w3 = t3;
        a0 += t0; a1 += t1; a2 += t2; a3 += t3;
      }
      // y10 = y0 + B*Z1*acc
      const float s0f = fmaf(z100, a0, fmaf(z101, a1, fmaf(z102, a2, z103 * a3)));
      const float s1f = fmaf(z110, a0, fmaf(z111, a1, fmaf(z112, a2, z113 * a3)));
      const float s2f = fmaf(z120, a0, fmaf(z121, a1, fmaf(z122, a2, z123 * a3)));
      const float s3f = fmaf(z130, a0, fmaf(z131, a1, fmaf(z132, a2, z133 * a3)));
      y[0] -= s0f;
      y[1] += s0f - s1f;
      y[2] += s1f - s2f;
      y[3] += s2f - s3f;
      y[4] += s3f;
      if (quad == 0) {
        *(f32x4*)&s_yr[slot][col][0] = *(const f32x4*)&y[0];
        s_yr[slot][col][4] = y[4];
      }
      // feat(k+1) -> liftT -> silu -> x stage
      if (k + 1 < KSTEPS) {
        s16x8 af = zf;
        if (quad == 0) {
          union { s16x8 v; unsigned u[4]; } afu;
          afu.u[0] = cvt2bf(urk1[0], urk1[1]);
          afu.u[1] = cvt2bf(urk1[2], y[0]);
          afu.u[2] = cvt2bf(y[1], y[2]);
          afu.u[3] = cvt2bf(y[3], y[4]);
          af = afu.v;
        }
        f32x4 x0 = MFMA(blft0, af, lbv0);
        f32x4 x1 = MFMA(blft1, af, lbv1);
        f32x4 s0, s1;
#pragma unroll
        for (int i = 0; i < 4; ++i) {
          float v0 = x0[i]; s0[i] = v0 * sigm(v0);
          float v1 = x1[i]; s1[i] = v1 * sigm(v1);
        }
        uint2 xp0, xp1;
        xp0.x = cvt2bf(s0[0], s0[1]); xp0.y = cvt2bf(s0[2], s0[3]);
        xp1.x = cvt2bf(s1[0], s1[1]); xp1.y = cvt2bf(s1[2], s1[3]);
        *(uint2*)((char*)s_Ax + xw0) = xp0;
        *(uint2*)((char*)s_Ax + xw1) = xp1;
      }
      __builtin_amdgcn_s_setprio(0);
    } else {
      // gh(k+1) for this wave's tile (in wave-7's shadow)
#pragma unroll
      for (int s = 0; s < 4; ++s) {
        ar = MFMA(bhh_r[s], ah[s], ar);
        az = MFMA(bhh_z[s], ah[s], az);
        angh = MFMA(bhh_n[s], ah[s], angh);
      }
      if (w == 1 && lane < 16) {  // stage u/dt for step k+2 (drain shadowed)
        int kn2 = (k + 2 < KSTEPS) ? k + 2 : KSTEPS - 1;
        const float* up = &u_seq[((size_t)(r0 + lane) * KSTEPS + kn2) * 3];
        f32x4 uv;
        uv[0] = up[0]; uv[1] = up[1]; uv[2] = up[2];
        uv[3] = dt_seq[(size_t)(r0 + lane) * KSTEPS + kn2];
        *(f32x4*)&s_ur[sC][lane][0] = uv;
      }
      if (w == 0 && k > 0) {  // store step k-1 outputs from the ring
        const int km = k - 1, slot = km & 1;
#pragma unroll
        for (int rep = 0; rep < 2; ++rep) {
          int idx = lane + rep * 64;
          int row = idx >> 3, c = idx & 7;
          th_out[((size_t)(r0 + row) * KSTEPS + km) * 8 + c] = s_thr[slot][row][c];
        }
        {
          int idx = lane;
          int row = idx / 5, c = idx - row * 5;
          y_out[((size_t)(r0 + row) * KSTEPS + km) * 5 + c] = s_yr[slot][row][c];
        }
        if (lane < 16) {
          int idx = 64 + lane;
          int row = idx / 5, c = idx - row * 5;
          y_out[((size_t)(r0 + row) * KSTEPS + km) * 5 + c] = s_yr[slot][row][c];
        }
      }
    }
    __syncthreads();  // B_x: x(k+1) staged, s_Ah + s_ur[sC] reusable
    int st = sA; sA = sB; sB = sC; sC = st;
  }

  // flush step-511 outputs
  if (w == 0) {
    const int km = KSTEPS - 1, slot = km & 1;
#pragma unroll
    for (int rep = 0; rep < 2; ++rep) {
      int idx = lane + rep * 64;
      int row = idx >> 3, c = idx & 7;
      th_out[((size_t)(r0 + row) * KSTEPS + km) * 8 + c] = s_thr[slot][row][c];
    }
    {
      int idx = lane;
      int row = idx / 5, c = idx - row * 5;
      y_out[((size_t)(r0 + row) * KSTEPS + km) * 5 + c] = s_yr[slot][row][c];
    }
    if (lane < 16) {
      int idx = 64 + lane;
      int row = idx / 5, c = idx - row * 5;
      y_out[((size_t)(r0 + row) * KSTEPS + km) * 5 + c] = s_yr[slot][row][c];
    }
  }
}

extern "C" void kernel_launch(void* const* d_in, const int* in_sizes, int n_in,
                              void* d_out, int out_size, void* d_ws, size_t ws_size,
                              hipStream_t stream) {
  const float* y0 = (const float*)d_in[0];
  const float* u_seq = (const float*)d_in[1];
  const float* dt_seq = (const float*)d_in[2];
  const float* lift_W = (const float*)d_in[3];
  const float* lift_b = (const float*)d_in[4];
  const float* W_ih = (const float*)d_in[5];
  const float* W_hh = (const float*)d_in[6];
  const float* b_ih = (const float*)d_in[7];
  const float* b_hh = (const float*)d_in[8];
  const float* head_W = (const float*)d_in[9];
  const float* head_b = (const float*)d_in[10];
  const float* jumpW = (const float*)d_in[11];

  float* y_out = (float*)d_out;                    // (4096, 512, 5)
  float* th_out = y_out + (size_t)4096 * 512 * 5;  // (4096, 512, 8)

  rnn_scan_kernel<<<dim3(256), dim3(NTH), 0, stream>>>(
      y0, u_seq, dt_seq, lift_W, lift_b, W_ih, W_hh, b_ih, b_hh, head_W,
      head_b, jumpW, y_out, th_out);
}

// Round 5
// 959.914 us; speedup vs baseline: 1.1481x; 1.0663x over previous
//
#include <hip/hip_runtime.h>

// SimpleRNN: B=4096, K=512, U=3, P=5, H=128, L=32, N_SUB=10
// 256 blocks x 512 threads (8 waves), 16 batch rows/block, 1 block/CU.
// "T-scheme": all GEMMs computed transposed (weights as MFMA A-operand,
// activations as B-operand) so D has batch-row in lane&15 and out-col in
// regs. LDS fragment buffers are lane-major: consumer lane l reads its 16B
// block at l*16 (conflict-free b128); producers write one ds_write_b64.
//
// R1: RK4 is linear in y: substep == y <- max(M y, 0); collapsed via
//     T = C*B (4x4 tridiag) to M = I5 + B*P*C, P = hs*Z1.
// R2: double-head MFMA gives every lane all 8 rates (no ds_swizzle).
// R3: flux-space iteration (4-dim w~ <- G w~, G = I + hs*T*Z1); u/dt staged
//     by wave 1 into a 3-slot LDS ring.
// R4->R5: v_pk_fma_f32 + op_sel broadcast for flux iteration / G build /
//     Z1*acc apply (matvec output pair IS the next broadcast source: 2x f32
//     rate, zero repack); head MFMAs as 8 independent accumulators + tree
//     add. R4's ds_bpermute x-rebuild REVERTED (pull semantics broke quads
//     1/2: source-side cndmask can't serve two consumers per instruction);
//     wave 7 reads its x-fragment via ds_read_b128 like all other waves.

#define KSTEPS 512
#define NTH 512

typedef short s16x8 __attribute__((ext_vector_type(8)));
typedef short s16x4 __attribute__((ext_vector_type(4)));
typedef float f32x4 __attribute__((ext_vector_type(4)));
typedef float f32x2 __attribute__((ext_vector_type(2)));

__device__ __forceinline__ unsigned short f2bf(float f) {
  union { float f; unsigned u; } v; v.f = f;
  unsigned r = v.u + 0x7FFFu + ((v.u >> 16) & 1u);  // RNE
  return (unsigned short)(r >> 16);
}
__device__ __forceinline__ unsigned cvt2bf(float lo, float hi) {
  unsigned r;
  asm("v_cvt_pk_bf16_f32 %0, %1, %2" : "=v"(r) : "v"(lo), "v"(hi));
  return r;
}
__device__ __forceinline__ float ex2(float x) {
#if __has_builtin(__builtin_amdgcn_exp2f)
  return __builtin_amdgcn_exp2f(x);
#else
  return exp2f(x);
#endif
}
__device__ __forceinline__ float rcp_(float x) {
#if __has_builtin(__builtin_amdgcn_rcpf)
  return __builtin_amdgcn_rcpf(x);
#else
  return 1.0f / x;
#endif
}
__device__ __forceinline__ float sigm(float x) {
  return rcp_(1.0f + ex2(-1.44269504088896f * x));
}
__device__ __forceinline__ float tanh_(float x) {
  return fmaf(2.0f, rcp_(1.0f + ex2(-2.88539008177793f * x)), -1.0f);
}
__device__ __forceinline__ f32x4 splat4(float v) { f32x4 r = {v, v, v, v}; return r; }
__device__ __forceinline__ f32x4 MFMA(s16x8 a, s16x8 b, f32x4 c) {
  return __builtin_amdgcn_mfma_f32_16x16x32_bf16(a, b, c, 0, 0, 0);
}
__device__ __forceinline__ s16x8 bfrag_g(const float* __restrict__ src8) {
  s16x8 r;
#pragma unroll
  for (int j = 0; j < 8; ++j) r[j] = (short)f2bf(src8[j]);
  return r;
}

// ---- packed f32 math with op_sel B-broadcast ----
// default VOP3P: op_sel:[0,0,0] op_sel_hi:[1,1,1] (elementwise)
// _blo: B.lo used for BOTH halves; _bhi: B.hi used for BOTH halves.
__device__ __forceinline__ f32x2 pkfma_blo(f32x2 a, f32x2 b, f32x2 c) {
  f32x2 d;
  asm("v_pk_fma_f32 %0, %1, %2, %3 op_sel:[0,0,0] op_sel_hi:[1,0,1]"
      : "=v"(d) : "v"(a), "v"(b), "v"(c));
  return d;
}
__device__ __forceinline__ f32x2 pkfma_bhi(f32x2 a, f32x2 b, f32x2 c) {
  f32x2 d;
  asm("v_pk_fma_f32 %0, %1, %2, %3 op_sel:[0,1,0] op_sel_hi:[1,1,1]"
      : "=v"(d) : "v"(a), "v"(b), "v"(c));
  return d;
}
__device__ __forceinline__ f32x2 pkmul_blo(f32x2 a, f32x2 b) {
  f32x2 d;
  asm("v_pk_mul_f32 %0, %1, %2 op_sel:[0,0] op_sel_hi:[1,0]"
      : "=v"(d) : "v"(a), "v"(b));
  return d;
}
__device__ __forceinline__ f32x2 pkmul_bhi(f32x2 a, f32x2 b) {
  f32x2 d;
  asm("v_pk_mul_f32 %0, %1, %2 op_sel:[0,1] op_sel_hi:[1,1]"
      : "=v"(d) : "v"(a), "v"(b));
  return d;
}
__device__ __forceinline__ f32x2 pkadd(f32x2 a, f32x2 b) {
  f32x2 d;
  asm("v_pk_add_f32 %0, %1, %2" : "=v"(d) : "v"(a), "v"(b));
  return d;
}

__global__ __launch_bounds__(NTH, 2) void rnn_scan_kernel(
    const float* __restrict__ y0, const float* __restrict__ u_seq,
    const float* __restrict__ dt_seq, const float* __restrict__ lift_W,
    const float* __restrict__ lift_b, const float* __restrict__ W_ih,
    const float* __restrict__ W_hh, const float* __restrict__ b_ih,
    const float* __restrict__ b_hh, const float* __restrict__ head_W,
    const float* __restrict__ head_b, const float* __restrict__ jumpW,
    float* __restrict__ y_out, float* __restrict__ th_out) {
  __shared__ __align__(16) unsigned short s_Ah[4096];  // h: k=128 -> 4 frags
  __shared__ __align__(16) unsigned short s_Ax[1024];  // x: k=32  -> 1 frag
  __shared__ __align__(16) float s_thr[2][16][8];      // theta ring
  __shared__ __align__(16) float s_yr[2][16][8];       // y ring (padded)
  __shared__ __align__(16) float s_ur[3][16][4];       // u/dt ring (3 slots)

  const int tid = threadIdx.x;
  const int w = tid >> 6;      // wave 0..7; wave 7 = critical wave
  const int lane = tid & 63;
  const int quad = lane >> 4;
  const int col = lane & 15;   // = batch row in the T-scheme
  const int r0 = blockIdx.x << 4;

  s16x8 zf;
#pragma unroll
  for (int j = 0; j < 8; ++j) zf[j] = 0;

  // ---- weight A-frags: A[m=out-col@lane&15][k=quad*8+j] ----
  s16x8 bih_r = bfrag_g(&W_ih[(w * 16 + col) * 32 + quad * 8]);
  s16x8 bih_z = bfrag_g(&W_ih[((8 + w) * 16 + col) * 32 + quad * 8]);
  s16x8 bih_n = bfrag_g(&W_ih[((16 + w) * 16 + col) * 32 + quad * 8]);
  s16x8 bhh_r[4], bhh_z[4], bhh_n[4], bhdF[4], bhdR[4];
#pragma unroll
  for (int s = 0; s < 4; ++s) {
    bhh_r[s] = bfrag_g(&W_hh[(w * 16 + col) * 128 + s * 32 + quad * 8]);
    bhh_z[s] = bfrag_g(&W_hh[((8 + w) * 16 + col) * 128 + s * 32 + quad * 8]);
    bhh_n[s] = bfrag_g(&W_hh[((16 + w) * 16 + col) * 128 + s * 32 + quad * 8]);
    // head rows replicated mod 4: every lane receives kf1..4 / kr1..4.
    bhdF[s] = bfrag_g(&head_W[(col & 3) * 128 + s * 32 + quad * 8]);
    bhdR[s] = bfrag_g(&head_W[(4 + (col & 3)) * 128 + s * 32 + quad * 8]);
  }
  s16x8 blft0 = (quad == 0) ? bfrag_g(&lift_W[col * 8]) : zf;
  s16x8 blft1 = (quad == 0) ? bfrag_g(&lift_W[(16 + col) * 8]) : zf;

  // ---- per-(quad,i) biases ----
  f32x4 brz_r, brz_z, bn_iv, bn_hv, lbv0, lbv1, hbF, hbR;
#pragma unroll
  for (int i = 0; i < 4; ++i) {
    int g = w * 16 + quad * 4 + i;
    brz_r[i] = b_ih[g] + b_hh[g];
    brz_z[i] = b_ih[128 + g] + b_hh[128 + g];
    bn_iv[i] = b_ih[256 + g];
    bn_hv[i] = b_hh[256 + g];
    lbv0[i] = lift_b[quad * 4 + i];
    lbv1[i] = lift_b[16 + quad * 4 + i];
    hbF[i] = head_b[i];
    hbR[i] = head_b[4 + i];
  }
  float J[15];
#pragma unroll
  for (int i = 0; i < 15; ++i) J[i] = jumpW[i];

  // producer LDS byte offsets
  const int hwoff = (((w >> 1) * 64 + ((w & 1) * 2 + (quad >> 1)) * 16 + col) << 4) +
                    ((quad & 1) << 3);
  const int xw0 = ((((quad >> 1)) * 16 + col) << 4) + ((quad & 1) << 3);
  const int xw1 = (((2 + (quad >> 1)) * 16 + col) << 4) + ((quad & 1) << 3);

  // persistent state
  f32x4 ar = brz_r, az = brz_z, angi = bn_iv, angh = bn_hv;
  f32x4 h_reg = splat4(0.0f);
  float y[5] = {0.f, 0.f, 0.f, 0.f, 0.f};

  // ---- prologue ----
  if (w == 1 && lane < 16) {
#pragma unroll
    for (int pk = 0; pk < 2; ++pk) {
      const float* up = &u_seq[((size_t)(r0 + lane) * KSTEPS + pk) * 3];
      f32x4 uv;
      uv[0] = up[0]; uv[1] = up[1]; uv[2] = up[2];
      uv[3] = dt_seq[(size_t)(r0 + lane) * KSTEPS + pk];
      *(f32x4*)&s_ur[pk][lane][0] = uv;
    }
  }
  if (w == 7) {
    float uc0 = 0.f, uc1 = 0.f, uc2 = 0.f;
    if (quad == 0) {
      const float* yp = &y0[(r0 + col) * 5];
#pragma unroll
      for (int i = 0; i < 5; ++i) y[i] = yp[i] + 0.01f;
      const float* up = &u_seq[((size_t)(r0 + col) * KSTEPS) * 3];
      uc0 = up[0]; uc1 = up[1]; uc2 = up[2];
    }
    s16x8 af = zf;
    if (quad == 0) {
      union { s16x8 v; unsigned u[4]; } afu;
      afu.u[0] = cvt2bf(uc0, uc1);
      afu.u[1] = cvt2bf(uc2, y[0]);
      afu.u[2] = cvt2bf(y[1], y[2]);
      afu.u[3] = cvt2bf(y[3], y[4]);
      af = afu.v;
    }
    f32x4 x0 = MFMA(blft0, af, lbv0);
    f32x4 x1 = MFMA(blft1, af, lbv1);
    f32x4 s0, s1;
#pragma unroll
    for (int i = 0; i < 4; ++i) {
      float v0 = x0[i]; s0[i] = v0 * sigm(v0);
      float v1 = x1[i]; s1[i] = v1 * sigm(v1);
    }
    uint2 xp0, xp1;
    xp0.x = cvt2bf(s0[0], s0[1]); xp0.y = cvt2bf(s0[2], s0[3]);
    xp1.x = cvt2bf(s1[0], s1[1]); xp1.y = cvt2bf(s1[2], s1[3]);
    *(uint2*)((char*)s_Ax + xw0) = xp0;
    *(uint2*)((char*)s_Ax + xw1) = xp1;
  }
  __syncthreads();  // B_x(0)

  int sA = 0, sB = 1, sC = 2;  // u-ring slots: k%3, (k+1)%3, (k+2)%3

#pragma unroll 1
  for (int k = 0; k < KSTEPS; ++k) {
    // ======== phase 1: gi + gates + h stage (all waves) ========
    {
      s16x8 xf = *(const s16x8*)((const char*)s_Ax + lane * 16);
      ar = MFMA(bih_r, xf, ar);
      az = MFMA(bih_z, xf, az);
      angi = MFMA(bih_n, xf, angi);
    }
    {
      f32x4 hf;
#pragma unroll
      for (int i = 0; i < 4; ++i) {
        float r = sigm(ar[i]);
        float z = sigm(az[i]);
        float n = tanh_(fmaf(r, angh[i], angi[i]));
        float hn = fmaf(z, h_reg[i] - n, n);
        h_reg[i] = hn;
        hf[i] = hn;
      }
      uint2 hp;
      hp.x = cvt2bf(hf[0], hf[1]);
      hp.y = cvt2bf(hf[2], hf[3]);
      *(uint2*)((char*)s_Ah + hwoff) = hp;
    }
    ar = brz_r; az = brz_z; angi = bn_iv; angh = bn_hv;  // reset for k+1
    __syncthreads();  // B_h

    // ======== phase 2 ========
    s16x8 ah[4];
#pragma unroll
    for (int s = 0; s < 4; ++s)
      ah[s] = *(const s16x8*)((const char*)s_Ah + (s * 64 + lane) * 16);

    if (w == 7) {
      __builtin_amdgcn_s_setprio(1);
      f32x4 urk = *(const f32x4*)&s_ur[sA][col][0];
      f32x4 urk1 = *(const f32x4*)&s_ur[sB][col][0];
      // head: 8 independent MFMAs (tree-add later; depth 1 chain)
      f32x4 hdF0 = MFMA(bhdF[0], ah[0], hbF);
      f32x4 hdF1 = MFMA(bhdF[1], ah[1], splat4(0.0f));
      f32x4 hdF2 = MFMA(bhdF[2], ah[2], splat4(0.0f));
      f32x4 hdF3 = MFMA(bhdF[3], ah[3], splat4(0.0f));
      f32x4 hdR0 = MFMA(bhdR[0], ah[0], hbR);
      f32x4 hdR1 = MFMA(bhdR[1], ah[1], splat4(0.0f));
      f32x4 hdR2 = MFMA(bhdR[2], ah[2], splat4(0.0f));
      f32x4 hdR3 = MFMA(bhdR[3], ah[3], splat4(0.0f));
      // own gh(k+1) issues under head latency
#pragma unroll
      for (int s = 0; s < 4; ++s) {
        ar = MFMA(bhh_r[s], ah[s], ar);
        az = MFMA(bhh_z[s], ah[s], az);
        angh = MFMA(bhh_n[s], ah[s], angh);
      }
      f32x4 hdF = (hdF0 + hdF1) + (hdF2 + hdF3);
      f32x4 hdR = (hdR0 + hdR1) + (hdR2 + hdR3);
      f32x4 tvF, tvR;
#pragma unroll
      for (int i = 0; i < 4; ++i) {
        tvF[i] = fmaf(2.99f, sigm(hdF[i]), 0.01f);
        tvR[i] = fmaf(2.99f, sigm(hdR[i]), 0.01f);
      }
      const int slot = k & 1;
      if (quad == 0) {
        *(f32x4*)&s_thr[slot][col][0] = tvF;
        *(f32x4*)&s_thr[slot][col][4] = tvR;
      }
      const float F0 = tvF[0], F1 = tvF[1], F2 = tvF[2], F3 = tvF[3];
      const float R0 = tvR[0], R1 = tvR[1], R2 = tvR[2], R3 = tvR[3];
      // jump
#pragma unroll
      for (int i = 0; i < 5; ++i)
        y[i] += urk[0] * J[i] + urk[1] * J[5 + i] + urk[2] * J[10 + i];
      const float hs = urk[3] * 0.1f;

      // ---- Z1 = I + c2 T(I + c3 T(I + c4 T)) (scalar, as R3) ----
      const float TD0 = -(F0 + R0), TD1 = -(F1 + R1), TD2 = -(F2 + R2), TD3 = -(F3 + R3);
      const float c4 = 0.25f * hs, c3 = hs * (1.0f / 3.0f), c2 = 0.5f * hs;
      const float d30 = fmaf(c4, TD0, 1.f), d31 = fmaf(c4, TD1, 1.f);
      const float d32 = fmaf(c4, TD2, 1.f), d33 = fmaf(c4, TD3, 1.f);
      const float l31 = c4 * F1, l32 = c4 * F2, l33 = c4 * F3;
      const float u30 = c4 * R0, u31 = c4 * R1, u32 = c4 * R2;
      const float w300 = fmaf(TD0, d30, R0 * l31);
      const float w301 = fmaf(TD0, u30, R0 * d31);
      const float w302 = R0 * u31;
      const float w310 = fmaf(F1, d30, TD1 * l31);
      const float w311 = fmaf(F1, u30, fmaf(TD1, d31, R1 * l32));
      const float w312 = fmaf(TD1, u31, R1 * d32);
      const float w313 = R1 * u32;
      const float w320 = F2 * l31;
      const float w321 = fmaf(F2, d31, TD2 * l32);
      const float w322 = fmaf(F2, u31, fmaf(TD2, d32, R2 * l33));
      const float w323 = fmaf(TD2, u32, R2 * d33);
      const float w331 = F3 * l32;
      const float w332 = fmaf(F3, d32, TD3 * l33);
      const float w333 = fmaf(F3, u32, TD3 * d33);
      const float e20 = fmaf(c3, w300, 1.f), e21 = fmaf(c3, w311, 1.f);
      const float e22 = fmaf(c3, w322, 1.f), e23 = fmaf(c3, w333, 1.f);
      const float a201 = c3 * w301, a202 = c3 * w302;
      const float a210 = c3 * w310, a212 = c3 * w312, a213 = c3 * w313;
      const float a220 = c3 * w320, a221 = c3 * w321, a223 = c3 * w323;
      const float a231 = c3 * w331, a232 = c3 * w332;
      const float w200 = fmaf(TD0, e20, R0 * a210);
      const float w201 = fmaf(TD0, a201, R0 * e21);
      const float w202 = fmaf(TD0, a202, R0 * a212);
      const float w203 = R0 * a213;
      const float w210 = fmaf(F1, e20, fmaf(TD1, a210, R1 * a220));
      const float w211 = fmaf(F1, a201, fmaf(TD1, e21, R1 * a221));
      const float w212 = fmaf(F1, a202, fmaf(TD1, a212, R1 * e22));
      const float w213 = fmaf(TD1, a213, R1 * a223);
      const float w220 = fmaf(F2, a210, TD2 * a220);
      const float w221 = fmaf(F2, e21, fmaf(TD2, a221, R2 * a231));
      const float w222 = fmaf(F2, a212, fmaf(TD2, e22, R2 * a232));
      const float w223 = fmaf(F2, a213, fmaf(TD2, a223, R2 * e23));
      const float w230 = F3 * a220;
      const float w231 = fmaf(F3, a221, TD3 * a231);
      const float w232 = fmaf(F3, e22, TD3 * a232);
      const float w233 = fmaf(F3, a223, TD3 * e23);
      const float z100 = fmaf(c2, w200, 1.f), z101 = c2 * w201, z102 = c2 * w202, z103 = c2 * w203;
      const float z110 = c2 * w210, z111 = fmaf(c2, w211, 1.f), z112 = c2 * w212, z113 = c2 * w213;
      const float z120 = c2 * w220, z121 = c2 * w221, z122 = fmaf(c2, w222, 1.f), z123 = c2 * w223;
      const float z130 = c2 * w230, z131 = c2 * w231, z132 = c2 * w232, z133 = fmaf(c2, w233, 1.f);

      // ---- packed Z1 columns (reused for G build and final apply) ----
      f32x2 cZa0 = {z100, z110}, cZb0 = {z120, z130};
      f32x2 cZa1 = {z101, z111}, cZb1 = {z121, z131};
      f32x2 cZa2 = {z102, z112}, cZb2 = {z122, z132};
      f32x2 cZa3 = {z103, z113}, cZb3 = {z123, z133};

      const float FH0 = hs * F0, FH1 = hs * F1, FH2 = hs * F2, FH3 = hs * F3;
      const float RH0 = hs * R0, RH1 = hs * R1, RH2 = hs * R2, RH3 = hs * R3;
      const float TDH0 = -(FH0 + RH0), TDH1 = -(FH1 + RH1);
      const float TDH2 = -(FH2 + RH2), TDH3 = -(FH3 + RH3);
      // packed row-constant pairs for G = I + hs*T*Z1 (hs folded per-term)
      f32x2 pA01 = {TDH0, FH1}, pB01 = {RH0, TDH1}, pC01 = {0.f, RH1};
      f32x2 pA23 = {FH2, 0.f}, pB23 = {TDH2, FH3}, pC23 = {RH2, TDH3};
      // G columns: cGja = (g0j,g1j), cGjb = (g2j,g3j)
      f32x2 cG0a = pkfma_blo(pC01, cZb0, pkfma_bhi(pB01, cZa0, pkmul_blo(pA01, cZa0)));
      f32x2 cG1a = pkfma_blo(pC01, cZb1, pkfma_bhi(pB01, cZa1, pkmul_blo(pA01, cZa1)));
      f32x2 cG2a = pkfma_blo(pC01, cZb2, pkfma_bhi(pB01, cZa2, pkmul_blo(pA01, cZa2)));
      f32x2 cG3a = pkfma_blo(pC01, cZb3, pkfma_bhi(pB01, cZa3, pkmul_blo(pA01, cZa3)));
      f32x2 cG0b = pkfma_bhi(pC23, cZb0, pkfma_blo(pB23, cZb0, pkmul_bhi(pA23, cZa0)));
      f32x2 cG1b = pkfma_bhi(pC23, cZb1, pkfma_blo(pB23, cZb1, pkmul_bhi(pA23, cZa1)));
      f32x2 cG2b = pkfma_bhi(pC23, cZb2, pkfma_blo(pB23, cZb2, pkmul_bhi(pA23, cZa2)));
      f32x2 cG3b = pkfma_bhi(pC23, cZb3, pkfma_blo(pB23, cZb3, pkmul_bhi(pA23, cZa3)));
      cG0a[0] += 1.0f;  // diag
      cG1a[1] += 1.0f;
      cG2b[0] += 1.0f;
      cG3b[1] += 1.0f;

      // w~0 = hs*C*y (clamp is a no-op: M>=0 entrywise, y>=0)
      const float w0v = fmaf(FH0, y[0], -(RH0 * y[1]));
      const float w1v = fmaf(FH1, y[1], -(RH1 * y[2]));
      const float w2v = fmaf(FH2, y[2], -(RH2 * y[3]));
      const float w3v = fmaf(FH3, y[3], -(RH3 * y[4]));
      f32x2 W01 = {w0v, w1v}, W23 = {w2v, w3v};
      f32x2 A01 = W01, A23 = W23;
#pragma unroll
      for (int ss = 0; ss < 9; ++ss) {
        f32x2 m01 = pkfma_blo(cG0a, W01,
                    pkfma_bhi(cG1a, W01,
                    pkfma_blo(cG2a, W23, pkmul_bhi(cG3a, W23))));
        f32x2 m23 = pkfma_blo(cG0b, W01,
                    pkfma_bhi(cG1b, W01,
                    pkfma_blo(cG2b, W23, pkmul_bhi(cG3b, W23))));
        W01 = m01; W23 = m23;
        A01 = pkadd(A01, m01); A23 = pkadd(A23, m23);
      }
      // s = Z1 * acc  (packed)
      f32x2 s01 = pkfma_blo(cZa0, A01,
                  pkfma_bhi(cZa1, A01,
                  pkfma_blo(cZa2, A23, pkmul_bhi(cZa3, A23))));
      f32x2 s23 = pkfma_blo(cZb0, A01,
                  pkfma_bhi(cZb1, A01,
                  pkfma_blo(cZb2, A23, pkmul_bhi(cZb3, A23))));
      const float s0f = s01[0], s1f = s01[1], s2f = s23[0], s3f = s23[1];
      y[0] -= s0f;
      y[1] += s0f - s1f;
      y[2] += s1f - s2f;
      y[3] += s2f - s3f;
      y[4] += s3f;
      if (quad == 0) {
        *(f32x4*)&s_yr[slot][col][0] = *(const f32x4*)&y[0];
        s_yr[slot][col][4] = y[4];
      }
      // feat(k+1) -> liftT -> silu -> x stage
      if (k + 1 < KSTEPS) {
        s16x8 af = zf;
        if (quad == 0) {
          union { s16x8 v; unsigned u[4]; } afu;
          afu.u[0] = cvt2bf(urk1[0], urk1[1]);
          afu.u[1] = cvt2bf(urk1[2], y[0]);
          afu.u[2] = cvt2bf(y[1], y[2]);
          afu.u[3] = cvt2bf(y[3], y[4]);
          af = afu.v;
        }
        f32x4 x0 = MFMA(blft0, af, lbv0);
        f32x4 x1 = MFMA(blft1, af, lbv1);
        f32x4 s0, s1;
#pragma unroll
        for (int i = 0; i < 4; ++i) {
          float v0 = x0[i]; s0[i] = v0 * sigm(v0);
          float v1 = x1[i]; s1[i] = v1 * sigm(v1);
        }
        uint2 xp0, xp1;
        xp0.x = cvt2bf(s0[0], s0[1]); xp0.y = cvt2bf(s0[2], s0[3]);
        xp1.x = cvt2bf(s1[0], s1[1]); xp1.y = cvt2bf(s1[2], s1[3]);
        *(uint2*)((char*)s_Ax + xw0) = xp0;
        *(uint2*)((char*)s_Ax + xw1) = xp1;
      }
      __builtin_amdgcn_s_setprio(0);
    } else {
      // gh(k+1) for this wave's tile (in wave-7's shadow)
#pragma unroll
      for (int s = 0; s < 4; ++s) {
        ar = MFMA(bhh_r[s], ah[s], ar);
        az = MFMA(bhh_z[s], ah[s], az);
        angh = MFMA(bhh_n[s], ah[s], angh);
      }
      if (w == 1 && lane < 16) {  // stage u/dt for step k+2
        int kn2 = (k + 2 < KSTEPS) ? k + 2 : KSTEPS - 1;
        const float* up = &u_seq[((size_t)(r0 + lane) * KSTEPS + kn2) * 3];
        f32x4 uv;
        uv[0] = up[0]; uv[1] = up[1]; uv[2] = up[2];
        uv[3] = dt_seq[(size_t)(r0 + lane) * KSTEPS + kn2];
        *(f32x4*)&s_ur[sC][lane][0] = uv;
      }
      if (w == 0 && k > 0) {  // store step k-1 outputs from the ring
        const int km = k - 1, slot = km & 1;
#pragma unroll
        for (int rep = 0; rep < 2; ++rep) {
          int idx = lane + rep * 64;
          int row = idx >> 3, c = idx & 7;
          th_out[((size_t)(r0 + row) * KSTEPS + km) * 8 + c] = s_thr[slot][row][c];
        }
        {
          int idx = lane;
          int row = idx / 5, c = idx - row * 5;
          y_out[((size_t)(r0 + row) * KSTEPS + km) * 5 + c] = s_yr[slot][row][c];
        }
        if (lane < 16) {
          int idx = 64 + lane;
          int row = idx / 5, c = idx - row * 5;
          y_out[((size_t)(r0 + row) * KSTEPS + km) * 5 + c] = s_yr[slot][row][c];
        }
      }
    }
    __syncthreads();  // B_x: x(k+1) staged, s_Ah + s_ur[sC] reusable
    int st = sA; sA = sB; sB = sC; sC = st;
  }

  // flush step-511 outputs
  if (w == 0) {
    const int km = KSTEPS - 1, slot = km & 1;
#pragma unroll
    for (int rep = 0; rep < 2; ++rep) {
      int idx = lane + rep * 64;
      int row = idx >> 3, c = idx & 7;
      th_out[((size_t)(r0 + row) * KSTEPS + km) * 8 + c] = s_thr[slot][row][c];
    }
    {
      int idx = lane;
      int row = idx / 5, c = idx - row * 5;
      y_out[((size_t)(r0 + row) * KSTEPS + km) * 5 + c] = s_yr[slot][row][c];
    }
    if (lane < 16) {
      int idx = 64 + lane;
      int row = idx / 5, c = idx - row * 5;
      y_out[((size_t)(r0 + row) * KSTEPS + km) * 5 + c] = s_yr[slot][row][c];
    }
  }
}

extern "C" void kernel_launch(void* const* d_in, const int* in_sizes, int n_in,
                              void* d_out, int out_size, void* d_ws, size_t ws_size,
                              hipStream_t stream) {
  const float* y0 = (const float*)d_in[0];
  const float* u_seq = (const float*)d_in[1];
  const float* dt_seq = (const float*)d_in[2];
  const float* lift_W = (const float*)d_in[3];
  const float* lift_b = (const float*)d_in[4];
  const float* W_ih = (const float*)d_in[5];
  const float* W_hh = (const float*)d_in[6];
  const float* b_ih = (const float*)d_in[7];
  const float* b_hh = (const float*)d_in[8];
  const float* head_W = (const float*)d_in[9];
  const float* head_b = (const float*)d_in[10];
  const float* jumpW = (const float*)d_in[11];

  float* y_out = (float*)d_out;                    // (4096, 512, 5)
  float* th_out = y_out + (size_t)4096 * 512 * 5;  // (4096, 512, 8)

  rnn_scan_kernel<<<dim3(256), dim3(NTH), 0, stream>>>(
      y0, u_seq, dt_seq, lift_W, lift_b, W_ih, W_hh, b_ih, b_hh, head_W,
      head_b, jumpW, y_out, th_out);
}

// Round 8
// 959.357 us; speedup vs baseline: 1.1488x; 1.0006x over previous
//
#include <hip/hip_runtime.h>

// SimpleRNN: B=4096, K=512, U=3, P=5, H=128, L=32, N_SUB=10
// 256 blocks x 512 threads (8 waves), 16 batch rows/block, 1 block/CU.
// "T-scheme": all GEMMs transposed (weights = MFMA A-operand, activations =
// B-operand): D has batch-row in lane&15, out-col in regs+quad.
//
// R1: RK4 linear in y -> M = I5 + B*(hs*Z1)*C via T = C*B (4x4 tridiag).
// R2: double-head MFMA: every lane gets all 8 rates directly.
// R3: flux-space iteration (w~ <- G w~, G = I + hs*T*Z1); u/dt LDS ring.
// R5: v_pk_fma_f32 + op_sel broadcast for flux iter / G build / Z1 apply;
//     head as 8 independent MFMA accumulators. PASSED @ 894 us.
// R8: BISECTION ROUND. R6/R7 both failed; common suspects are (b) bias
//     C-folding and (c) packed tree/sigm. This kernel is R5 + (b) ONLY,
//     byte-minimal: the accumulator-reset line is deleted, bn_iv folds into
//     the phase-1 n-gate MFMA, and s=0 of each gh chain takes the bias as
//     its C operand. Everything else identical to R5.

#define KSTEPS 512
#define NTH 512

typedef short s16x8 __attribute__((ext_vector_type(8)));
typedef short s16x4 __attribute__((ext_vector_type(4)));
typedef float f32x4 __attribute__((ext_vector_type(4)));
typedef float f32x2 __attribute__((ext_vector_type(2)));

__device__ __forceinline__ unsigned short f2bf(float f) {
  union { float f; unsigned u; } v; v.f = f;
  unsigned r = v.u + 0x7FFFu + ((v.u >> 16) & 1u);  // RNE
  return (unsigned short)(r >> 16);
}
__device__ __forceinline__ unsigned cvt2bf(float lo, float hi) {
  unsigned r;
  asm("v_cvt_pk_bf16_f32 %0, %1, %2" : "=v"(r) : "v"(lo), "v"(hi));
  return r;
}
__device__ __forceinline__ float ex2(float x) {
#if __has_builtin(__builtin_amdgcn_exp2f)
  return __builtin_amdgcn_exp2f(x);
#else
  return exp2f(x);
#endif
}
__device__ __forceinline__ float rcp_(float x) {
#if __has_builtin(__builtin_amdgcn_rcpf)
  return __builtin_amdgcn_rcpf(x);
#else
  return 1.0f / x;
#endif
}
__device__ __forceinline__ float sigm(float x) {
  return rcp_(1.0f + ex2(-1.44269504088896f * x));
}
__device__ __forceinline__ float tanh_(float x) {
  return fmaf(2.0f, rcp_(1.0f + ex2(-2.88539008177793f * x)), -1.0f);
}
__device__ __forceinline__ f32x4 splat4(float v) { f32x4 r = {v, v, v, v}; return r; }
__device__ __forceinline__ f32x4 MFMA(s16x8 a, s16x8 b, f32x4 c) {
  return __builtin_amdgcn_mfma_f32_16x16x32_bf16(a, b, c, 0, 0, 0);
}
__device__ __forceinline__ s16x8 bfrag_g(const float* __restrict__ src8) {
  s16x8 r;
#pragma unroll
  for (int j = 0; j < 8; ++j) r[j] = (short)f2bf(src8[j]);
  return r;
}

// ---- packed f32 math with op_sel B-broadcast ----
__device__ __forceinline__ f32x2 pkfma_blo(f32x2 a, f32x2 b, f32x2 c) {
  f32x2 d;
  asm("v_pk_fma_f32 %0, %1, %2, %3 op_sel:[0,0,0] op_sel_hi:[1,0,1]"
      : "=v"(d) : "v"(a), "v"(b), "v"(c));
  return d;
}
__device__ __forceinline__ f32x2 pkfma_bhi(f32x2 a, f32x2 b, f32x2 c) {
  f32x2 d;
  asm("v_pk_fma_f32 %0, %1, %2, %3 op_sel:[0,1,0] op_sel_hi:[1,1,1]"
      : "=v"(d) : "v"(a), "v"(b), "v"(c));
  return d;
}
__device__ __forceinline__ f32x2 pkmul_blo(f32x2 a, f32x2 b) {
  f32x2 d;
  asm("v_pk_mul_f32 %0, %1, %2 op_sel:[0,0] op_sel_hi:[1,0]"
      : "=v"(d) : "v"(a), "v"(b));
  return d;
}
__device__ __forceinline__ f32x2 pkmul_bhi(f32x2 a, f32x2 b) {
  f32x2 d;
  asm("v_pk_mul_f32 %0, %1, %2 op_sel:[0,1] op_sel_hi:[1,1]"
      : "=v"(d) : "v"(a), "v"(b));
  return d;
}
__device__ __forceinline__ f32x2 pkadd(f32x2 a, f32x2 b) {
  f32x2 d;
  asm("v_pk_add_f32 %0, %1, %2" : "=v"(d) : "v"(a), "v"(b));
  return d;
}

__global__ __launch_bounds__(NTH, 2) void rnn_scan_kernel(
    const float* __restrict__ y0, const float* __restrict__ u_seq,
    const float* __restrict__ dt_seq, const float* __restrict__ lift_W,
    const float* __restrict__ lift_b, const float* __restrict__ W_ih,
    const float* __restrict__ W_hh, const float* __restrict__ b_ih,
    const float* __restrict__ b_hh, const float* __restrict__ head_W,
    const float* __restrict__ head_b, const float* __restrict__ jumpW,
    float* __restrict__ y_out, float* __restrict__ th_out) {
  __shared__ __align__(16) unsigned short s_Ah[4096];  // h: k=128 -> 4 frags
  __shared__ __align__(16) unsigned short s_Ax[1024];  // x: k=32  -> 1 frag
  __shared__ __align__(16) float s_thr[2][16][8];      // theta ring
  __shared__ __align__(16) float s_yr[2][16][8];       // y ring
  __shared__ __align__(16) float s_ur[3][16][4];       // u/dt ring (3 slots)

  const int tid = threadIdx.x;
  const int w = tid >> 6;      // wave 0..7; wave 7 = critical wave
  const int lane = tid & 63;
  const int quad = lane >> 4;
  const int col = lane & 15;   // = batch row in the T-scheme
  const int r0 = blockIdx.x << 4;

  s16x8 zf;
#pragma unroll
  for (int j = 0; j < 8; ++j) zf[j] = 0;

  // ---- weight A-frags: A[m=out-col@lane&15][k=quad*8+j] ----
  s16x8 bih_r = bfrag_g(&W_ih[(w * 16 + col) * 32 + quad * 8]);
  s16x8 bih_z = bfrag_g(&W_ih[((8 + w) * 16 + col) * 32 + quad * 8]);
  s16x8 bih_n = bfrag_g(&W_ih[((16 + w) * 16 + col) * 32 + quad * 8]);
  s16x8 bhh_r[4], bhh_z[4], bhh_n[4], bhdF[4], bhdR[4];
#pragma unroll
  for (int s = 0; s < 4; ++s) {
    bhh_r[s] = bfrag_g(&W_hh[(w * 16 + col) * 128 + s * 32 + quad * 8]);
    bhh_z[s] = bfrag_g(&W_hh[((8 + w) * 16 + col) * 128 + s * 32 + quad * 8]);
    bhh_n[s] = bfrag_g(&W_hh[((16 + w) * 16 + col) * 128 + s * 32 + quad * 8]);
    // head rows replicated mod 4: every lane receives kf1..4 / kr1..4.
    bhdF[s] = bfrag_g(&head_W[(col & 3) * 128 + s * 32 + quad * 8]);
    bhdR[s] = bfrag_g(&head_W[(4 + (col & 3)) * 128 + s * 32 + quad * 8]);
  }
  s16x8 blft0 = (quad == 0) ? bfrag_g(&lift_W[col * 8]) : zf;
  s16x8 blft1 = (quad == 0) ? bfrag_g(&lift_W[(16 + col) * 8]) : zf;

  // ---- per-(quad,i) biases ----
  f32x4 brz_r, brz_z, bn_iv, bn_hv, lbv0, lbv1, hbF, hbR;
#pragma unroll
  for (int i = 0; i < 4; ++i) {
    int g = w * 16 + quad * 4 + i;
    brz_r[i] = b_ih[g] + b_hh[g];
    brz_z[i] = b_ih[128 + g] + b_hh[128 + g];
    bn_iv[i] = b_ih[256 + g];
    bn_hv[i] = b_hh[256 + g];
    lbv0[i] = lift_b[quad * 4 + i];
    lbv1[i] = lift_b[16 + quad * 4 + i];
    hbF[i] = head_b[i];
    hbR[i] = head_b[4 + i];
  }
  float J[15];
#pragma unroll
  for (int i = 0; i < 15; ++i) J[i] = jumpW[i];

  // producer LDS byte offsets
  const int hwoff = (((w >> 1) * 64 + ((w & 1) * 2 + (quad >> 1)) * 16 + col) << 4) +
                    ((quad & 1) << 3);
  const int xw0 = ((((quad >> 1)) * 16 + col) << 4) + ((quad & 1) << 3);
  const int xw1 = (((2 + (quad >> 1)) * 16 + col) << 4) + ((quad & 1) << 3);

  // persistent state (ar/az/angh carry bias+gh across barriers; no resets)
  f32x4 ar = brz_r, az = brz_z, angi = bn_iv, angh = bn_hv;
  f32x4 h_reg = splat4(0.0f);
  float y[5] = {0.f, 0.f, 0.f, 0.f, 0.f};

  // ---- prologue ----
  if (w == 1 && lane < 16) {
#pragma unroll
    for (int pk = 0; pk < 2; ++pk) {
      const float* up = &u_seq[((size_t)(r0 + lane) * KSTEPS + pk) * 3];
      f32x4 uv;
      uv[0] = up[0]; uv[1] = up[1]; uv[2] = up[2];
      uv[3] = dt_seq[(size_t)(r0 + lane) * KSTEPS + pk];
      *(f32x4*)&s_ur[pk][lane][0] = uv;
    }
  }
  if (w == 7) {
    float uc0 = 0.f, uc1 = 0.f, uc2 = 0.f;
    if (quad == 0) {
      const float* yp = &y0[(r0 + col) * 5];
#pragma unroll
      for (int i = 0; i < 5; ++i) y[i] = yp[i] + 0.01f;
      const float* up = &u_seq[((size_t)(r0 + col) * KSTEPS) * 3];
      uc0 = up[0]; uc1 = up[1]; uc2 = up[2];
    }
    s16x8 af = zf;
    if (quad == 0) {
      union { s16x8 v; unsigned u[4]; } afu;
      afu.u[0] = cvt2bf(uc0, uc1);
      afu.u[1] = cvt2bf(uc2, y[0]);
      afu.u[2] = cvt2bf(y[1], y[2]);
      afu.u[3] = cvt2bf(y[3], y[4]);
      af = afu.v;
    }
    f32x4 x0 = MFMA(blft0, af, lbv0);
    f32x4 x1 = MFMA(blft1, af, lbv1);
    f32x4 s0, s1;
#pragma unroll
    for (int i = 0; i < 4; ++i) {
      float v0 = x0[i]; s0[i] = v0 * sigm(v0);
      float v1 = x1[i]; s1[i] = v1 * sigm(v1);
    }
    uint2 xp0, xp1;
    xp0.x = cvt2bf(s0[0], s0[1]); xp0.y = cvt2bf(s0[2], s0[3]);
    xp1.x = cvt2bf(s1[0], s1[1]); xp1.y = cvt2bf(s1[2], s1[3]);
    *(uint2*)((char*)s_Ax + xw0) = xp0;
    *(uint2*)((char*)s_Ax + xw1) = xp1;
  }
  __syncthreads();  // B_x(0)

  int sA = 0, sB = 1, sC = 2;  // u-ring slots

#pragma unroll 1
  for (int k = 0; k < KSTEPS; ++k) {
    // ======== phase 1: gi + gates + h stage (all waves) ========
    {
      s16x8 xf = *(const s16x8*)((const char*)s_Ax + lane * 16);
      ar = MFMA(bih_r, xf, ar);        // carried C = bias + gh(k)
      az = MFMA(bih_z, xf, az);
      angi = MFMA(bih_n, xf, bn_iv);   // bias folded directly
    }
    {
      f32x4 hf;
#pragma unroll
      for (int i = 0; i < 4; ++i) {
        float r = sigm(ar[i]);
        float z = sigm(az[i]);
        float n = tanh_(fmaf(r, angh[i], angi[i]));
        float hn = fmaf(z, h_reg[i] - n, n);
        h_reg[i] = hn;
        hf[i] = hn;
      }
      uint2 hp;
      hp.x = cvt2bf(hf[0], hf[1]);
      hp.y = cvt2bf(hf[2], hf[3]);
      *(uint2*)((char*)s_Ah + hwoff) = hp;
    }
    __syncthreads();  // B_h

    // ======== phase 2 ========
    s16x8 ah[4];
#pragma unroll
    for (int s = 0; s < 4; ++s)
      ah[s] = *(const s16x8*)((const char*)s_Ah + (s * 64 + lane) * 16);

    if (w == 7) {
      __builtin_amdgcn_s_setprio(1);
      f32x4 urk = *(const f32x4*)&s_ur[sA][col][0];
      f32x4 urk1 = *(const f32x4*)&s_ur[sB][col][0];
      // head: 8 independent MFMAs
      f32x4 hdF0 = MFMA(bhdF[0], ah[0], hbF);
      f32x4 hdF1 = MFMA(bhdF[1], ah[1], splat4(0.0f));
      f32x4 hdF2 = MFMA(bhdF[2], ah[2], splat4(0.0f));
      f32x4 hdF3 = MFMA(bhdF[3], ah[3], splat4(0.0f));
      f32x4 hdR0 = MFMA(bhdR[0], ah[0], hbR);
      f32x4 hdR1 = MFMA(bhdR[1], ah[1], splat4(0.0f));
      f32x4 hdR2 = MFMA(bhdR[2], ah[2], splat4(0.0f));
      f32x4 hdR3 = MFMA(bhdR[3], ah[3], splat4(0.0f));
      // own gh(k+1) issues under head latency, biases C-folded
      ar = MFMA(bhh_r[0], ah[0], brz_r);
      az = MFMA(bhh_z[0], ah[0], brz_z);
      angh = MFMA(bhh_n[0], ah[0], bn_hv);
#pragma unroll
      for (int s = 1; s < 4; ++s) {
        ar = MFMA(bhh_r[s], ah[s], ar);
        az = MFMA(bhh_z[s], ah[s], az);
        angh = MFMA(bhh_n[s], ah[s], angh);
      }
      f32x4 hdF = (hdF0 + hdF1) + (hdF2 + hdF3);
      f32x4 hdR = (hdR0 + hdR1) + (hdR2 + hdR3);
      f32x4 tvF, tvR;
#pragma unroll
      for (int i = 0; i < 4; ++i) {
        tvF[i] = fmaf(2.99f, sigm(hdF[i]), 0.01f);
        tvR[i] = fmaf(2.99f, sigm(hdR[i]), 0.01f);
      }
      const int slot = k & 1;
      if (quad == 0) {
        *(f32x4*)&s_thr[slot][col][0] = tvF;
        *(f32x4*)&s_thr[slot][col][4] = tvR;
      }
      const float F0 = tvF[0], F1 = tvF[1], F2 = tvF[2], F3 = tvF[3];
      const float R0 = tvR[0], R1 = tvR[1], R2 = tvR[2], R3 = tvR[3];
      // jump
#pragma unroll
      for (int i = 0; i < 5; ++i)
        y[i] += urk[0] * J[i] + urk[1] * J[5 + i] + urk[2] * J[10 + i];
      const float hs = urk[3] * 0.1f;

      // ---- Z1 = I + c2 T(I + c3 T(I + c4 T)) (scalar) ----
      const float TD0 = -(F0 + R0), TD1 = -(F1 + R1), TD2 = -(F2 + R2), TD3 = -(F3 + R3);
      const float c4 = 0.25f * hs, c3 = hs * (1.0f / 3.0f), c2 = 0.5f * hs;
      const float d30 = fmaf(c4, TD0, 1.f), d31 = fmaf(c4, TD1, 1.f);
      const float d32 = fmaf(c4, TD2, 1.f), d33 = fmaf(c4, TD3, 1.f);
      const float l31 = c4 * F1, l32 = c4 * F2, l33 = c4 * F3;
      const float u30 = c4 * R0, u31 = c4 * R1, u32 = c4 * R2;
      const float w300 = fmaf(TD0, d30, R0 * l31);
      const float w301 = fmaf(TD0, u30, R0 * d31);
      const float w302 = R0 * u31;
      const float w310 = fmaf(F1, d30, TD1 * l31);
      const float w311 = fmaf(F1, u30, fmaf(TD1, d31, R1 * l32));
      const float w312 = fmaf(TD1, u31, R1 * d32);
      const float w313 = R1 * u32;
      const float w320 = F2 * l31;
      const float w321 = fmaf(F2, d31, TD2 * l32);
      const float w322 = fmaf(F2, u31, fmaf(TD2, d32, R2 * l33));
      const float w323 = fmaf(TD2, u32, R2 * d33);
      const float w331 = F3 * l32;
      const float w332 = fmaf(F3, d32, TD3 * l33);
      const float w333 = fmaf(F3, u32, TD3 * d33);
      const float e20 = fmaf(c3, w300, 1.f), e21 = fmaf(c3, w311, 1.f);
      const float e22 = fmaf(c3, w322, 1.f), e23 = fmaf(c3, w333, 1.f);
      const float a201 = c3 * w301, a202 = c3 * w302;
      const float a210 = c3 * w310, a212 = c3 * w312, a213 = c3 * w313;
      const float a220 = c3 * w320, a221 = c3 * w321, a223 = c3 * w323;
      const float a231 = c3 * w331, a232 = c3 * w332;
      const float w200 = fmaf(TD0, e20, R0 * a210);
      const float w201 = fmaf(TD0, a201, R0 * e21);
      const float w202 = fmaf(TD0, a202, R0 * a212);
      const float w203 = R0 * a213;
      const float w210 = fmaf(F1, e20, fmaf(TD1, a210, R1 * a220));
      const float w211 = fmaf(F1, a201, fmaf(TD1, e21, R1 * a221));
      const float w212 = fmaf(F1, a202, fmaf(TD1, a212, R1 * e22));
      const float w213 = fmaf(TD1, a213, R1 * a223);
      const float w220 = fmaf(F2, a210, TD2 * a220);
      const float w221 = fmaf(F2, e21, fmaf(TD2, a221, R2 * a231));
      const float w222 = fmaf(F2, a212, fmaf(TD2, e22, R2 * a232));
      const float w223 = fmaf(F2, a213, fmaf(TD2, a223, R2 * e23));
      const float w230 = F3 * a220;
      const float w231 = fmaf(F3, a221, TD3 * a231);
      const float w232 = fmaf(F3, e22, TD3 * a232);
      const float w233 = fmaf(F3, a223, TD3 * e23);
      const float z100 = fmaf(c2, w200, 1.f), z101 = c2 * w201, z102 = c2 * w202, z103 = c2 * w203;
      const float z110 = c2 * w210, z111 = fmaf(c2, w211, 1.f), z112 = c2 * w212, z113 = c2 * w213;
      const float z120 = c2 * w220, z121 = c2 * w221, z122 = fmaf(c2, w222, 1.f), z123 = c2 * w223;
      const float z130 = c2 * w230, z131 = c2 * w231, z132 = c2 * w232, z133 = fmaf(c2, w233, 1.f);

      // ---- packed Z1 columns ----
      f32x2 cZa0 = {z100, z110}, cZb0 = {z120, z130};
      f32x2 cZa1 = {z101, z111}, cZb1 = {z121, z131};
      f32x2 cZa2 = {z102, z112}, cZb2 = {z122, z132};
      f32x2 cZa3 = {z103, z113}, cZb3 = {z123, z133};

      const float FH0 = hs * F0, FH1 = hs * F1, FH2 = hs * F2, FH3 = hs * F3;
      const float RH0 = hs * R0, RH1 = hs * R1, RH2 = hs * R2, RH3 = hs * R3;
      const float TDH0 = -(FH0 + RH0), TDH1 = -(FH1 + RH1);
      const float TDH2 = -(FH2 + RH2), TDH3 = -(FH3 + RH3);
      f32x2 pA01 = {TDH0, FH1}, pB01 = {RH0, TDH1}, pC01 = {0.f, RH1};
      f32x2 pA23 = {FH2, 0.f}, pB23 = {TDH2, FH3}, pC23 = {RH2, TDH3};
      f32x2 cG0a = pkfma_blo(pC01, cZb0, pkfma_bhi(pB01, cZa0, pkmul_blo(pA01, cZa0)));
      f32x2 cG1a = pkfma_blo(pC01, cZb1, pkfma_bhi(pB01, cZa1, pkmul_blo(pA01, cZa1)));
      f32x2 cG2a = pkfma_blo(pC01, cZb2, pkfma_bhi(pB01, cZa2, pkmul_blo(pA01, cZa2)));
      f32x2 cG3a = pkfma_blo(pC01, cZb3, pkfma_bhi(pB01, cZa3, pkmul_blo(pA01, cZa3)));
      f32x2 cG0b = pkfma_bhi(pC23, cZb0, pkfma_blo(pB23, cZb0, pkmul_bhi(pA23, cZa0)));
      f32x2 cG1b = pkfma_bhi(pC23, cZb1, pkfma_blo(pB23, cZb1, pkmul_bhi(pA23, cZa1)));
      f32x2 cG2b = pkfma_bhi(pC23, cZb2, pkfma_blo(pB23, cZb2, pkmul_bhi(pA23, cZa2)));
      f32x2 cG3b = pkfma_bhi(pC23, cZb3, pkfma_blo(pB23, cZb3, pkmul_bhi(pA23, cZa3)));
      cG0a[0] += 1.0f;
      cG1a[1] += 1.0f;
      cG2b[0] += 1.0f;
      cG3b[1] += 1.0f;

      // w~0 = hs*C*y
      const float w0v = fmaf(FH0, y[0], -(RH0 * y[1]));
      const float w1v = fmaf(FH1, y[1], -(RH1 * y[2]));
      const float w2v = fmaf(FH2, y[2], -(RH2 * y[3]));
      const float w3v = fmaf(FH3, y[3], -(RH3 * y[4]));
      f32x2 W01 = {w0v, w1v}, W23 = {w2v, w3v};
      f32x2 A01 = W01, A23 = W23;
#pragma unroll
      for (int ss = 0; ss < 9; ++ss) {
        f32x2 m01 = pkfma_blo(cG0a, W01,
                    pkfma_bhi(cG1a, W01,
                    pkfma_blo(cG2a, W23, pkmul_bhi(cG3a, W23))));
        f32x2 m23 = pkfma_blo(cG0b, W01,
                    pkfma_bhi(cG1b, W01,
                    pkfma_blo(cG2b, W23, pkmul_bhi(cG3b, W23))));
        W01 = m01; W23 = m23;
        A01 = pkadd(A01, m01); A23 = pkadd(A23, m23);
      }
      f32x2 s01 = pkfma_blo(cZa0, A01,
                  pkfma_bhi(cZa1, A01,
                  pkfma_blo(cZa2, A23, pkmul_bhi(cZa3, A23))));
      f32x2 s23 = pkfma_blo(cZb0, A01,
                  pkfma_bhi(cZb1, A01,
                  pkfma_blo(cZb2, A23, pkmul_bhi(cZb3, A23))));
      const float s0f = s01[0], s1f = s01[1], s2f = s23[0], s3f = s23[1];
      y[0] -= s0f;
      y[1] += s0f - s1f;
      y[2] += s1f - s2f;
      y[3] += s2f - s3f;
      y[4] += s3f;
      if (quad == 0) {
        *(f32x4*)&s_yr[slot][col][0] = *(const f32x4*)&y[0];
        s_yr[slot][col][4] = y[4];
      }
      // feat(k+1) -> liftT -> silu -> x stage
      if (k + 1 < KSTEPS) {
        s16x8 af = zf;
        if (quad == 0) {
          union { s16x8 v; unsigned u[4]; } afu;
          afu.u[0] = cvt2bf(urk1[0], urk1[1]);
          afu.u[1] = cvt2bf(urk1[2], y[0]);
          afu.u[2] = cvt2bf(y[1], y[2]);
          afu.u[3] = cvt2bf(y[3], y[4]);
          af = afu.v;
        }
        f32x4 x0 = MFMA(blft0, af, lbv0);
        f32x4 x1 = MFMA(blft1, af, lbv1);
        f32x4 s0, s1;
#pragma unroll
        for (int i = 0; i < 4; ++i) {
          float v0 = x0[i]; s0[i] = v0 * sigm(v0);
          float v1 = x1[i]; s1[i] = v1 * sigm(v1);
        }
        uint2 xp0, xp1;
        xp0.x = cvt2bf(s0[0], s0[1]); xp0.y = cvt2bf(s0[2], s0[3]);
        xp1.x = cvt2bf(s1[0], s1[1]); xp1.y = cvt2bf(s1[2], s1[3]);
        *(uint2*)((char*)s_Ax + xw0) = xp0;
        *(uint2*)((char*)s_Ax + xw1) = xp1;
      }
      __builtin_amdgcn_s_setprio(0);
    } else {
      // gh(k+1) for this wave's tile, biases C-folded
      ar = MFMA(bhh_r[0], ah[0], brz_r);
      az = MFMA(bhh_z[0], ah[0], brz_z);
      angh = MFMA(bhh_n[0], ah[0], bn_hv);
#pragma unroll
      for (int s = 1; s < 4; ++s) {
        ar = MFMA(bhh_r[s], ah[s], ar);
        az = MFMA(bhh_z[s], ah[s], az);
        angh = MFMA(bhh_n[s], ah[s], angh);
      }
      if (w == 1 && lane < 16) {  // stage u/dt for step k+2
        int kn2 = (k + 2 < KSTEPS) ? k + 2 : KSTEPS - 1;
        const float* up = &u_seq[((size_t)(r0 + lane) * KSTEPS + kn2) * 3];
        f32x4 uv;
        uv[0] = up[0]; uv[1] = up[1]; uv[2] = up[2];
        uv[3] = dt_seq[(size_t)(r0 + lane) * KSTEPS + kn2];
        *(f32x4*)&s_ur[sC][lane][0] = uv;
      }
      if (w == 0 && k > 0) {  // store step k-1 outputs from the ring
        const int km = k - 1, slot = km & 1;
#pragma unroll
        for (int rep = 0; rep < 2; ++rep) {
          int idx = lane + rep * 64;
          int row = idx >> 3, c = idx & 7;
          th_out[((size_t)(r0 + row) * KSTEPS + km) * 8 + c] = s_thr[slot][row][c];
        }
        {
          int idx = lane;
          int row = idx / 5, c = idx - row * 5;
          y_out[((size_t)(r0 + row) * KSTEPS + km) * 5 + c] = s_yr[slot][row][c];
        }
        if (lane < 16) {
          int idx = 64 + lane;
          int row = idx / 5, c = idx - row * 5;
          y_out[((size_t)(r0 + row) * KSTEPS + km) * 5 + c] = s_yr[slot][row][c];
        }
      }
    }
    __syncthreads();  // B_x: x(k+1) staged, s_Ah + s_ur[sC] reusable
    int st = sA; sA = sB; sB = sC; sC = st;
  }

  // flush step-511 outputs
  if (w == 0) {
    const int km = KSTEPS - 1, slot = km & 1;
#pragma unroll
    for (int rep = 0; rep < 2; ++rep) {
      int idx = lane + rep * 64;
      int row = idx >> 3, c = idx & 7;
      th_out[((size_t)(r0 + row) * KSTEPS + km) * 8 + c] = s_thr[slot][row][c];
    }
    {
      int idx = lane;
      int row = idx / 5, c = idx - row * 5;
      y_out[((size_t)(r0 + row) * KSTEPS + km) * 5 + c] = s_yr[slot][row][c];
    }
    if (lane < 16) {
      int idx = 64 + lane;
      int row = idx / 5, c = idx - row * 5;
      y_out[((size_t)(r0 + row) * KSTEPS + km) * 5 + c] = s_yr[slot][row][c];
    }
  }
}

extern "C" void kernel_launch(void* const* d_in, const int* in_sizes, int n_in,
                              void* d_out, int out_size, void* d_ws, size_t ws_size,
                              hipStream_t stream) {
  const float* y0 = (const float*)d_in[0];
  const float* u_seq = (const float*)d_in[1];
  const float* dt_seq = (const float*)d_in[2];
  const float* lift_W = (const float*)d_in[3];
  const float* lift_b = (const float*)d_in[4];
  const float* W_ih = (const float*)d_in[5];
  const float* W_hh = (const float*)d_in[6];
  const float* b_ih = (const float*)d_in[7];
  const float* b_hh = (const float*)d_in[8];
  const float* head_W = (const float*)d_in[9];
  const float* head_b = (const float*)d_in[10];
  const float* jumpW = (const float*)d_in[11];

  float* y_out = (float*)d_out;                    // (4096, 512, 5)
  float* th_out = y_out + (size_t)4096 * 512 * 5;  // (4096, 512, 8)

  rnn_scan_kernel<<<dim3(256), dim3(NTH), 0, stream>>>(
      y0, u_seq, dt_seq, lift_W, lift_b, W_ih, W_hh, b_ih, b_hh, head_W,
      head_b, jumpW, y_out, th_out);
}